// Round 2
// baseline (273.369 us; speedup 1.0000x reference)
//
#include <hip/hip_runtime.h>
#include <hip/hip_bf16.h>
#include <cstdint>
#include <cstddef>

#define N_NODES 50000
#define NEG_SLOPE 0.2f
#define NB 196            // buckets of 256 nodes: (50000+255)/256
#define BIN_CHUNK 8192    // edges per block in hist/bin kernels
#define SLICE_MAX 14336   // LDS slice capacity (mean ~4345, 3.3x headroom)

typedef float floatx4 __attribute__((ext_vector_type(4)));
typedef short shortx8 __attribute__((ext_vector_type(8)));

// ---- fp32 <-> bf16 helpers (RNE) --------------------------------------------
__device__ __forceinline__ unsigned short f2b(float f) {
    union { float f; unsigned u; } v; v.f = f;
    unsigned u = v.u;
    return (unsigned short)((u + 0x7FFFu + ((u >> 16) & 1u)) >> 16);
}
__device__ __forceinline__ float b2f(unsigned short b) {
    union { unsigned u; float f; } v; v.u = ((unsigned)b) << 16;
    return v.f;
}

// ---------------------------------------------------------------------------
// CSR build, bucketed multisplit.
// K1: bucket histogram (LDS per block, 196 global atomics per block)
// ---------------------------------------------------------------------------
__global__ __launch_bounds__(256) void bucket_hist_kernel(
    const int* __restrict__ ei, int E0, int E, int* __restrict__ bhist) {
    __shared__ int h[NB];
    int t = threadIdx.x;
    for (int i = t; i < NB; i += 256) h[i] = 0;
    __syncthreads();
    int base = blockIdx.x * BIN_CHUNK;
    int end = min(base + BIN_CHUNK, E);
    for (int e = base + t; e < end; e += 256) {
        int d = (e < E0) ? ei[E0 + e] : (e - E0);
        atomicAdd(&h[d >> 8], 1);
    }
    __syncthreads();
    for (int i = t; i < NB; i += 256)
        if (h[i]) atomicAdd(&bhist[i], h[i]);
}

// K2: scan 196 bucket counts -> bbase[NB+1], init bcursor, rowptr[N]=E
__global__ __launch_bounds__(256) void bucket_scan_kernel(
    const int* __restrict__ bhist, int* __restrict__ bbase,
    int* __restrict__ bcursor, int* __restrict__ rowptr, int E) {
    __shared__ int buf[256];
    int t = threadIdx.x;
    int v = (t < NB) ? bhist[t] : 0;
    int x = v;
    for (int off = 1; off < 256; off <<= 1) {
        buf[t] = x; __syncthreads();
        int y = (t >= off) ? buf[t - off] : 0;
        __syncthreads();
        x += y;
    }
    if (t < NB) {
        bbase[t] = x - v;      // exclusive
        bcursor[t] = x - v;
    }
    if (t == NB - 1) bbase[NB] = x;
    if (t == 0) rowptr[N_NODES] = E;
}

// K3: bin edges into bucket regions, packed src|(dst&255)<<16, burst writes
__global__ __launch_bounds__(256) void bin_kernel(
    const int* __restrict__ ei, int E0, int E,
    int* __restrict__ bcursor, unsigned int* __restrict__ ebuf) {
    __shared__ int h[NB];
    __shared__ int gbase[NB];
    int t = threadIdx.x;
    for (int i = t; i < NB; i += 256) h[i] = 0;
    __syncthreads();
    int base = blockIdx.x * BIN_CHUNK;
    int end = min(base + BIN_CHUNK, E);
    // pass 1: local histogram
    for (int e = base + t; e < end; e += 256) {
        int d = (e < E0) ? ei[E0 + e] : (e - E0);
        atomicAdd(&h[d >> 8], 1);
    }
    __syncthreads();
    // reserve global bursts
    for (int i = t; i < NB; i += 256) {
        int c = h[i];
        gbase[i] = c ? atomicAdd(&bcursor[i], c) : 0;
        h[i] = 0;  // reuse as local cursor
    }
    __syncthreads();
    // pass 2: re-read (L2-hot) and place
    for (int e = base + t; e < end; e += 256) {
        int s, d;
        if (e < E0) { s = ei[e]; d = ei[E0 + e]; }
        else        { s = e - E0; d = e - E0; }
        int b = d >> 8;
        int off = atomicAdd(&h[b], 1);
        ebuf[gbase[b] + off] = (unsigned)s | ((unsigned)(d & 255) << 16);
    }
}

// K4: one block per bucket: local deg-hist -> rowptr, LDS-staged CSR slice,
// fully-coalesced slice write. csrp keeps src|dloc<<16 packed (dloc needed
// by the edgew kernels to reconstruct dst per CSR slot).
__global__ __launch_bounds__(256) void build_kernel(
    const unsigned int* __restrict__ ebuf, const int* __restrict__ bbase,
    int* __restrict__ rowptr, unsigned int* __restrict__ csrp) {
    __shared__ int h[256];
    __shared__ int lrp[257];
    __shared__ unsigned int stag[SLICE_MAX];
    int b = blockIdx.x, t = threadIdx.x;
    int e0 = bbase[b], e1 = bbase[b + 1];
    int cnt = e1 - e0;
    int n0 = b << 8;
    h[t] = 0;
    __syncthreads();
    // pass A: per-node degree histogram
    for (int i = t; i < cnt; i += 256)
        atomicAdd(&h[ebuf[e0 + i] >> 16], 1);
    __syncthreads();
    // scan 256 -> exclusive lrp
    int v = h[t], x = v;
    __shared__ int buf[256];
    for (int off = 1; off < 256; off <<= 1) {
        buf[t] = x; __syncthreads();
        int y = (t >= off) ? buf[t - off] : 0;
        __syncthreads();
        x += y;
    }
    lrp[t] = x - v;
    if (t == 255) lrp[256] = x;
    h[t] = 0;  // reuse as fill counters
    __syncthreads();
    int n = n0 + t;
    if (n < N_NODES) rowptr[n] = e0 + lrp[t];
    // pass B: place packed (src|dloc<<16) into LDS slice
    for (int i = t; i < cnt; i += 256) {
        unsigned int v2 = ebuf[e0 + i];
        int dloc = v2 >> 16;
        int off = atomicAdd(&h[dloc], 1);
        stag[lrp[dloc] + off] = v2;
    }
    __syncthreads();
    // pass C: coalesced slice write-out
    for (int i = t; i < cnt; i += 256) csrp[e0 + i] = stag[i];
}

// ---------------------------------------------------------------------------
// Single-bf16 MFMA GEMM:  Cb[M,NREAL](bf16) = A[M,KK] x B[NREAL,KK]^T
// ---------------------------------------------------------------------------
template <int BM, int BN, int NREAL, int KK, typename InT>
__global__ __launch_bounds__(256) void gemm_bf16_kernel(
    const InT* __restrict__ A, const float* __restrict__ B,
    unsigned short* __restrict__ Cb, int M) {
    const int BK = 64, LDK = 72;
    const int NT = BN / 16;
    __shared__ unsigned short As[BM * LDK];
    __shared__ unsigned short Bs[BN * LDK];
    const int t = threadIdx.x;
    const int wave = t >> 6, lane = t & 63;
    const int lrow = lane & 15, lkg = lane >> 4;
    const int bm = blockIdx.x * BM;

    floatx4 acc[NT] = {};

    for (int k0 = 0; k0 < KK; k0 += BK) {
        __syncthreads();
        if constexpr (sizeof(InT) == 4) {
            for (int i = t; i < BM * 16; i += 256) {
                int r = i >> 4, c4 = (i & 15) << 2;
                int gr = bm + r;
                float4 v = make_float4(0.f, 0.f, 0.f, 0.f);
                if (gr < M) v = *(const float4*)&A[(size_t)gr * KK + k0 + c4];
                int o = r * LDK + c4;
                As[o] = f2b(v.x); As[o + 1] = f2b(v.y);
                As[o + 2] = f2b(v.z); As[o + 3] = f2b(v.w);
            }
        } else {
            for (int i = t; i < BM * 8; i += 256) {
                int r = i >> 3, c8 = (i & 7) << 3;
                int gr = bm + r;
                shortx8 v = {};
                if (gr < M) v = *(const shortx8*)&A[(size_t)gr * KK + k0 + c8];
                *(shortx8*)&As[r * LDK + c8] = v;
            }
        }
        for (int i = t; i < BN * 16; i += 256) {
            int r = i >> 4, c4 = (i & 15) << 2;
            float4 v = make_float4(0.f, 0.f, 0.f, 0.f);
            if (r < NREAL) v = *(const float4*)&B[(size_t)r * KK + k0 + c4];
            int o = r * LDK + c4;
            Bs[o] = f2b(v.x); Bs[o + 1] = f2b(v.y);
            Bs[o + 2] = f2b(v.z); Bs[o + 3] = f2b(v.w);
        }
        __syncthreads();

        for (int ks = 0; ks < BK; ks += 32) {
            int kc = ks + lkg * 8;
            int row = wave * 16 + lrow;
            shortx8 a = *(const shortx8*)&As[row * LDK + kc];
#pragma unroll
            for (int nt = 0; nt < NT; nt++) {
                shortx8 b = *(const shortx8*)&Bs[(nt * 16 + lrow) * LDK + kc];
                acc[nt] = __builtin_amdgcn_mfma_f32_16x16x32_bf16(a, b, acc[nt], 0, 0, 0);
            }
        }
    }
#pragma unroll
    for (int nt = 0; nt < NT; nt++)
#pragma unroll
        for (int r = 0; r < 4; r++) {
            int row = bm + wave * 16 + lkg * 4 + r;
            int col = nt * 16 + lrow;
            if (row < M && col < NREAL)
                Cb[(size_t)row * NREAL + col] = f2b(acc[nt][r]);
        }
}

// ---------------------------------------------------------------------------
// Attention coefficients from bf16 h
// ---------------------------------------------------------------------------
__global__ void att1_kernel(const unsigned short* __restrict__ h1b,
                            const float* __restrict__ att_src,
                            const float* __restrict__ att_dst,
                            float* __restrict__ a_src, float* __restrict__ a_dst,
                            int N) {
    int i = blockIdx.x * blockDim.x + threadIdx.x;
    if (i >= N * 4) return;
    int h = i & 3;
    const ushort4* hp = (const ushort4*)(h1b + (size_t)i * 32);
    const float4* as = (const float4*)(att_src + h * 32);
    const float4* ad = (const float4*)(att_dst + h * 32);
    float ssum = 0.f, dsum = 0.f;
#pragma unroll
    for (int j = 0; j < 8; j++) {
        ushort4 hv = hp[j];
        float4 av = as[j], dv = ad[j];
        float x0 = b2f(hv.x), x1 = b2f(hv.y), x2 = b2f(hv.z), x3 = b2f(hv.w);
        ssum += x0 * av.x + x1 * av.y + x2 * av.z + x3 * av.w;
        dsum += x0 * dv.x + x1 * dv.y + x2 * dv.z + x3 * dv.w;
    }
    a_src[i] = ssum;
    a_dst[i] = dsum;
}

__global__ void att2_kernel(const unsigned short* __restrict__ h2b,
                            const float* __restrict__ att_src,
                            const float* __restrict__ att_dst,
                            float* __restrict__ a_src, float* __restrict__ a_dst,
                            int N) {
    int n = blockIdx.x * blockDim.x + threadIdx.x;
    if (n >= N) return;
    const ushort4* hp = (const ushort4*)(h2b + (size_t)n * 40);
    const float4* as = (const float4*)att_src;
    const float4* ad = (const float4*)att_dst;
    float ssum = 0.f, dsum = 0.f;
#pragma unroll
    for (int j = 0; j < 10; j++) {
        ushort4 hv = hp[j];
        float4 av = as[j], dv = ad[j];
        float x0 = b2f(hv.x), x1 = b2f(hv.y), x2 = b2f(hv.z), x3 = b2f(hv.w);
        ssum += x0 * av.x + x1 * av.y + x2 * av.z + x3 * av.w;
        dsum += x0 * dv.x + x1 * dv.y + x2 * dv.z + x3 * dv.w;
    }
    a_src[n] = ssum;
    a_dst[n] = dsum;
}

// ---------------------------------------------------------------------------
// Edge-weight precompute (CSR order). Layer 1: w[e*4+h] for 4 heads.
// dst reconstructed from bucket id + packed dloc. Fully parallel, coalesced
// writes; removes the dependent a_src-gather + expf + shfl chain from agg1.
// ---------------------------------------------------------------------------
__global__ __launch_bounds__(256) void edgew1_kernel(
    const unsigned int* __restrict__ csrp, const int* __restrict__ bbase,
    const float* __restrict__ a_src, const float* __restrict__ a_dst,
    float* __restrict__ wexp) {
    int b = blockIdx.x;
    int i0 = bbase[b] * 4, i1 = bbase[b + 1] * 4;
    int dbase = b << 10;  // (b<<8)*4
    for (int i = i0 + blockIdx.y * 256 + threadIdx.x; i < i1; i += 256 * 8) {
        unsigned v = csrp[i >> 2];
        int h = i & 3;
        int s = (int)(v & 0xFFFFu);
        int dloc = (int)(v >> 16);
        float a = a_src[(s << 2) + h] + a_dst[dbase + (dloc << 2) + h];
        a = a > 0.f ? a : NEG_SLOPE * a;
        wexp[i] = __expf(a);
    }
}

// Layer 2: H=1, w[e].
__global__ __launch_bounds__(256) void edgew2_kernel(
    const unsigned int* __restrict__ csrp, const int* __restrict__ bbase,
    const float* __restrict__ a_src, const float* __restrict__ a_dst,
    float* __restrict__ wexp) {
    int b = blockIdx.x;
    int i0 = bbase[b], i1 = bbase[b + 1];
    int dbase = b << 8;
    for (int i = i0 + blockIdx.y * 256 + threadIdx.x; i < i1; i += 256 * 2) {
        unsigned v = csrp[i];
        float a = a_src[v & 0xFFFFu] + a_dst[dbase + (v >> 16)];
        a = a > 0.f ? a : NEG_SLOPE * a;
        wexp[i] = __expf(a);
    }
}

// ---------------------------------------------------------------------------
// Aggregation layer 1: one WAVE per node. v3: shfl-free — s and w loaded
// directly per lane (wave-broadcast, cache-hot), flat 8-deep gather batches.
// half 0 = even edges, half 1 = odd edges (same accumulation order as v2).
// ---------------------------------------------------------------------------
__global__ __launch_bounds__(256) void agg1_kernel(
    const unsigned short* __restrict__ h1b, const float* __restrict__ wexp,
    const unsigned int* __restrict__ csrp, const int* __restrict__ rowptr,
    const float* __restrict__ b1, unsigned short* __restrict__ zb, int N) {
    int wave = threadIdx.x >> 6, lane = threadIdx.x & 63;
    int n = blockIdx.x * 4 + wave;
    if (n >= N) return;
    int half = lane >> 5, pos = lane & 31, head = pos >> 3;
    int beg = rowptr[n], deg = rowptr[n + 1] - beg;

    const unsigned int* cp = csrp + beg;
    const float* wp = wexp + ((size_t)beg << 2) + head;

    floatx4 acc = {0.f, 0.f, 0.f, 0.f};
    float den = 0.f;
    int i = half;
    for (; i + 14 < deg; i += 16) {
        unsigned s_arr[8]; float w_arr[8]; ushort4 v_arr[8];
#pragma unroll
        for (int q = 0; q < 8; q++) {
            int e = i + (q << 1);
            s_arr[q] = cp[e] & 0xFFFFu;
            w_arr[q] = wp[e << 2];
        }
#pragma unroll
        for (int q = 0; q < 8; q++)
            v_arr[q] = *(const ushort4*)&h1b[(size_t)s_arr[q] * 128 + pos * 4];
#pragma unroll
        for (int q = 0; q < 8; q++) {
            float w = w_arr[q];
            den += w;
            acc.x += w * b2f(v_arr[q].x);
            acc.y += w * b2f(v_arr[q].y);
            acc.z += w * b2f(v_arr[q].z);
            acc.w += w * b2f(v_arr[q].w);
        }
    }
    for (; i < deg; i += 2) {
        unsigned s = cp[i] & 0xFFFFu;
        float w = wp[i << 2];
        ushort4 v = *(const ushort4*)&h1b[(size_t)s * 128 + pos * 4];
        den += w;
        acc.x += w * b2f(v.x);
        acc.y += w * b2f(v.y);
        acc.z += w * b2f(v.z);
        acc.w += w * b2f(v.w);
    }
    acc.x += __shfl_xor(acc.x, 32);
    acc.y += __shfl_xor(acc.y, 32);
    acc.z += __shfl_xor(acc.z, 32);
    acc.w += __shfl_xor(acc.w, 32);
    den   += __shfl_xor(den, 32);
    if (half == 0) {
        float inv = 1.f / den;
        float4 bb = *(const float4*)&b1[pos * 4];
        float o0 = fmaxf(acc.x * inv + bb.x, 0.f);
        float o1 = fmaxf(acc.y * inv + bb.y, 0.f);
        float o2 = fmaxf(acc.z * inv + bb.z, 0.f);
        float o3 = fmaxf(acc.w * inv + bb.w, 0.f);
        ushort4 r;
        r.x = f2b(o0); r.y = f2b(o1); r.z = f2b(o2); r.w = f2b(o3);
        *(ushort4*)&zb[(size_t)n * 128 + pos * 4] = r;
    }
}

// ---------------------------------------------------------------------------
// Aggregation layer 2: one wave per node, H=1, D=40. v3: shfl-free.
// ---------------------------------------------------------------------------
__global__ __launch_bounds__(256) void agg2_kernel(
    const unsigned short* __restrict__ h2b, const float* __restrict__ wexp,
    const unsigned int* __restrict__ csrp, const int* __restrict__ rowptr,
    const float* __restrict__ b2, float* __restrict__ out, int N) {
    int wave = threadIdx.x >> 6, lane = threadIdx.x & 63;
    int n = blockIdx.x * 4 + wave;
    if (n >= N) return;
    int half = lane >> 5, pos = lane & 31;
    int beg = rowptr[n], deg = rowptr[n + 1] - beg;

    const unsigned int* cp = csrp + beg;
    const float* wp = wexp + beg;

    float2 acc = {0.f, 0.f};
    float den = 0.f;
    int i = half;
    for (; i + 14 < deg; i += 16) {
        unsigned s_arr[8]; float w_arr[8]; ushort2 v_arr[8];
#pragma unroll
        for (int q = 0; q < 8; q++) {
            int e = i + (q << 1);
            s_arr[q] = cp[e] & 0xFFFFu;
            w_arr[q] = wp[e];
        }
        if (pos < 20) {
#pragma unroll
            for (int q = 0; q < 8; q++)
                v_arr[q] = *(const ushort2*)&h2b[(size_t)s_arr[q] * 40 + pos * 2];
        }
#pragma unroll
        for (int q = 0; q < 8; q++) {
            float w = w_arr[q];
            den += w;
            if (pos < 20) {
                acc.x += w * b2f(v_arr[q].x);
                acc.y += w * b2f(v_arr[q].y);
            }
        }
    }
    for (; i < deg; i += 2) {
        unsigned s = cp[i] & 0xFFFFu;
        float w = wp[i];
        den += w;
        if (pos < 20) {
            ushort2 v = *(const ushort2*)&h2b[(size_t)s * 40 + pos * 2];
            acc.x += w * b2f(v.x);
            acc.y += w * b2f(v.y);
        }
    }
    acc.x += __shfl_xor(acc.x, 32);
    acc.y += __shfl_xor(acc.y, 32);
    den   += __shfl_xor(den, 32);
    if (half == 0 && pos < 20) {
        float inv = 1.f / den;
        float2 bb = *(const float2*)&b2[pos * 2];
        float2 o;
        o.x = acc.x * inv + bb.x;
        o.y = acc.y * inv + bb.y;
        *(float2*)&out[(size_t)n * 40 + pos * 2] = o;
    }
}

// ---------------------------------------------------------------------------
extern "C" void kernel_launch(void* const* d_in, const int* in_sizes, int n_in,
                              void* d_out, int out_size, void* d_ws, size_t ws_size,
                              hipStream_t stream) {
    const float* x        = (const float*)d_in[0];
    const int*   ei       = (const int*)d_in[1];
    const float* W1       = (const float*)d_in[2];
    const float* att_src1 = (const float*)d_in[3];
    const float* att_dst1 = (const float*)d_in[4];
    const float* b1       = (const float*)d_in[5];
    const float* W2       = (const float*)d_in[6];
    const float* att_src2 = (const float*)d_in[7];
    const float* att_dst2 = (const float*)d_in[8];
    const float* b2       = (const float*)d_in[9];
    float* out = (float*)d_out;

    const int N  = N_NODES;
    const int E0 = in_sizes[1] / 2;
    const int E  = E0 + N;
    const int NBLK = (E + BIN_CHUNK - 1) / BIN_CHUNK;

    char* ws = (char*)d_ws;
    unsigned short* h1b = (unsigned short*)(ws + 0);          // 12,800,000
    unsigned short* zb  = (unsigned short*)(ws + 12800000);   // 12,800,000
    unsigned short* h2b = (unsigned short*)(ws + 25600000);   //  4,000,000
    float* a_src1 = (float*)(ws + 29600000);                  //    800,000
    float* a_dst1 = (float*)(ws + 30400000);                  //    800,000
    float* a_src2 = (float*)(ws + 31200000);                  //    200,000
    float* a_dst2 = (float*)(ws + 31400000);                  //    200,000
    int*   rowptr = (int*)(ws + 31600000);                    //    200,004
    int*   bhist  = (int*)(ws + 31800192);                    //        784
    int*   bbase  = (int*)(ws + 31801088);                    //        788
    int*   bcursor= (int*)(ws + 31801984);                    //        784
    unsigned int* ebuf = (unsigned int*)(ws + 31802880);      //  3,400,000
    unsigned int* csrp = (unsigned int*)(ws + 35202880);      //  3,400,000
    float* wexp1  = (float*)(ws + 38602880);                  // 13,600,000
    float* wexp2  = (float*)(ws + 52202880);                  //  3,400,000
    // total ~55.6 MB

    hipMemsetAsync(bhist, 0, NB * sizeof(int), stream);

    bucket_hist_kernel<<<NBLK, 256, 0, stream>>>(ei, E0, E, bhist);
    bucket_scan_kernel<<<1, 256, 0, stream>>>(bhist, bbase, bcursor, rowptr, E);
    bin_kernel<<<NBLK, 256, 0, stream>>>(ei, E0, E, bcursor, ebuf);
    build_kernel<<<NB, 256, 0, stream>>>(ebuf, bbase, rowptr, csrp);

    // layer 1: h1b = bf16(x @ W1^T)
    gemm_bf16_kernel<64, 128, 128, 256, float>
        <<<(N + 63) / 64, 256, 0, stream>>>(x, W1, h1b, N);
    att1_kernel<<<(N * 4 + 255) / 256, 256, 0, stream>>>(h1b, att_src1, att_dst1, a_src1, a_dst1, N);
    edgew1_kernel<<<dim3(NB, 8), 256, 0, stream>>>(csrp, bbase, a_src1, a_dst1, wexp1);
    agg1_kernel<<<(N + 3) / 4, 256, 0, stream>>>(h1b, wexp1, csrp, rowptr, b1, zb, N);

    // layer 2: h2b = bf16(zb @ W2^T)
    gemm_bf16_kernel<64, 48, 40, 128, unsigned short>
        <<<(N + 63) / 64, 256, 0, stream>>>(zb, W2, h2b, N);
    att2_kernel<<<(N + 255) / 256, 256, 0, stream>>>(h2b, att_src2, att_dst2, a_src2, a_dst2, N);
    edgew2_kernel<<<dim3(NB, 2), 256, 0, stream>>>(csrp, bbase, a_src2, a_dst2, wexp2);
    agg2_kernel<<<(N + 3) / 4, 256, 0, stream>>>(h2b, wexp2, csrp, rowptr, b2, out, N);
}

// Round 3
// 244.026 us; speedup vs baseline: 1.1202x; 1.1202x over previous
//
#include <hip/hip_runtime.h>
#include <hip/hip_bf16.h>
#include <cstdint>
#include <cstddef>

#define N_NODES 50000
#define NEG_SLOPE 0.2f
#define NB 196            // buckets of 256 nodes: (50000+255)/256
#define BIN_CHUNK 8192    // edges per block in hist/bin kernels
#define SLICE_MAX 14336   // LDS slice capacity (mean ~4345, 3.3x headroom)

typedef float floatx4 __attribute__((ext_vector_type(4)));
typedef short shortx8 __attribute__((ext_vector_type(8)));

// ---- fp32 <-> bf16 helpers (RNE) --------------------------------------------
__device__ __forceinline__ unsigned short f2b(float f) {
    union { float f; unsigned u; } v; v.f = f;
    unsigned u = v.u;
    return (unsigned short)((u + 0x7FFFu + ((u >> 16) & 1u)) >> 16);
}
__device__ __forceinline__ float b2f(unsigned short b) {
    union { unsigned u; float f; } v; v.u = ((unsigned)b) << 16;
    return v.f;
}

// ---------------------------------------------------------------------------
// CSR build, bucketed multisplit.
// K1: bucket histogram (LDS per block, 196 global atomics per block)
// ---------------------------------------------------------------------------
__global__ __launch_bounds__(256) void bucket_hist_kernel(
    const int* __restrict__ ei, int E0, int E, int* __restrict__ bhist) {
    __shared__ int h[NB];
    int t = threadIdx.x;
    for (int i = t; i < NB; i += 256) h[i] = 0;
    __syncthreads();
    int base = blockIdx.x * BIN_CHUNK;
    int end = min(base + BIN_CHUNK, E);
    for (int e = base + t; e < end; e += 256) {
        int d = (e < E0) ? ei[E0 + e] : (e - E0);
        atomicAdd(&h[d >> 8], 1);
    }
    __syncthreads();
    for (int i = t; i < NB; i += 256)
        if (h[i]) atomicAdd(&bhist[i], h[i]);
}

// K2: scan 196 bucket counts -> bbase[NB+1], init bcursor, rowptr[N]=E
__global__ __launch_bounds__(256) void bucket_scan_kernel(
    const int* __restrict__ bhist, int* __restrict__ bbase,
    int* __restrict__ bcursor, int* __restrict__ rowptr, int E) {
    __shared__ int buf[256];
    int t = threadIdx.x;
    int v = (t < NB) ? bhist[t] : 0;
    int x = v;
    for (int off = 1; off < 256; off <<= 1) {
        buf[t] = x; __syncthreads();
        int y = (t >= off) ? buf[t - off] : 0;
        __syncthreads();
        x += y;
    }
    if (t < NB) {
        bbase[t] = x - v;      // exclusive
        bcursor[t] = x - v;
    }
    if (t == NB - 1) bbase[NB] = x;
    if (t == 0) rowptr[N_NODES] = E;
}

// K3: bin edges into bucket regions, packed src|(dst&255)<<16, burst writes
__global__ __launch_bounds__(256) void bin_kernel(
    const int* __restrict__ ei, int E0, int E,
    int* __restrict__ bcursor, unsigned int* __restrict__ ebuf) {
    __shared__ int h[NB];
    __shared__ int gbase[NB];
    int t = threadIdx.x;
    for (int i = t; i < NB; i += 256) h[i] = 0;
    __syncthreads();
    int base = blockIdx.x * BIN_CHUNK;
    int end = min(base + BIN_CHUNK, E);
    // pass 1: local histogram
    for (int e = base + t; e < end; e += 256) {
        int d = (e < E0) ? ei[E0 + e] : (e - E0);
        atomicAdd(&h[d >> 8], 1);
    }
    __syncthreads();
    // reserve global bursts
    for (int i = t; i < NB; i += 256) {
        int c = h[i];
        gbase[i] = c ? atomicAdd(&bcursor[i], c) : 0;
        h[i] = 0;  // reuse as local cursor
    }
    __syncthreads();
    // pass 2: re-read (L2-hot) and place
    for (int e = base + t; e < end; e += 256) {
        int s, d;
        if (e < E0) { s = ei[e]; d = ei[E0 + e]; }
        else        { s = e - E0; d = e - E0; }
        int b = d >> 8;
        int off = atomicAdd(&h[b], 1);
        ebuf[gbase[b] + off] = (unsigned)s | ((unsigned)(d & 255) << 16);
    }
}

// K4: one block per bucket: local deg-hist -> rowptr, LDS-staged CSR slice,
// fully-coalesced slice write.
__global__ __launch_bounds__(256) void build_kernel(
    const unsigned int* __restrict__ ebuf, const int* __restrict__ bbase,
    int* __restrict__ rowptr, int* __restrict__ csr_src) {
    __shared__ int h[256];
    __shared__ int lrp[257];
    __shared__ int stag[SLICE_MAX];
    int b = blockIdx.x, t = threadIdx.x;
    int e0 = bbase[b], e1 = bbase[b + 1];
    int cnt = e1 - e0;
    int n0 = b << 8;
    h[t] = 0;
    __syncthreads();
    // pass A: per-node degree histogram
    for (int i = t; i < cnt; i += 256)
        atomicAdd(&h[ebuf[e0 + i] >> 16], 1);
    __syncthreads();
    // scan 256 -> exclusive lrp
    int v = h[t], x = v;
    __shared__ int buf[256];
    for (int off = 1; off < 256; off <<= 1) {
        buf[t] = x; __syncthreads();
        int y = (t >= off) ? buf[t - off] : 0;
        __syncthreads();
        x += y;
    }
    lrp[t] = x - v;
    if (t == 255) lrp[256] = x;
    h[t] = 0;  // reuse as fill counters
    __syncthreads();
    int n = n0 + t;
    if (n < N_NODES) rowptr[n] = e0 + lrp[t];
    // pass B: place srcs into LDS slice
    for (int i = t; i < cnt; i += 256) {
        unsigned int v2 = ebuf[e0 + i];
        int dloc = v2 >> 16;
        int off = atomicAdd(&h[dloc], 1);
        stag[lrp[dloc] + off] = (int)(v2 & 0xFFFFu);
    }
    __syncthreads();
    // pass C: coalesced slice write-out
    for (int i = t; i < cnt; i += 256) csr_src[e0 + i] = stag[i];
}

// ---------------------------------------------------------------------------
// Single-bf16 MFMA GEMM:  Cb[M,NREAL](bf16) = A[M,KK] x B[NREAL,KK]^T
// ---------------------------------------------------------------------------
template <int BM, int BN, int NREAL, int KK, typename InT>
__global__ __launch_bounds__(256) void gemm_bf16_kernel(
    const InT* __restrict__ A, const float* __restrict__ B,
    unsigned short* __restrict__ Cb, int M) {
    const int BK = 64, LDK = 72;
    const int NT = BN / 16;
    __shared__ unsigned short As[BM * LDK];
    __shared__ unsigned short Bs[BN * LDK];
    const int t = threadIdx.x;
    const int wave = t >> 6, lane = t & 63;
    const int lrow = lane & 15, lkg = lane >> 4;
    const int bm = blockIdx.x * BM;

    floatx4 acc[NT] = {};

    for (int k0 = 0; k0 < KK; k0 += BK) {
        __syncthreads();
        if constexpr (sizeof(InT) == 4) {
            for (int i = t; i < BM * 16; i += 256) {
                int r = i >> 4, c4 = (i & 15) << 2;
                int gr = bm + r;
                float4 v = make_float4(0.f, 0.f, 0.f, 0.f);
                if (gr < M) v = *(const float4*)&A[(size_t)gr * KK + k0 + c4];
                int o = r * LDK + c4;
                As[o] = f2b(v.x); As[o + 1] = f2b(v.y);
                As[o + 2] = f2b(v.z); As[o + 3] = f2b(v.w);
            }
        } else {
            for (int i = t; i < BM * 8; i += 256) {
                int r = i >> 3, c8 = (i & 7) << 3;
                int gr = bm + r;
                shortx8 v = {};
                if (gr < M) v = *(const shortx8*)&A[(size_t)gr * KK + k0 + c8];
                *(shortx8*)&As[r * LDK + c8] = v;
            }
        }
        for (int i = t; i < BN * 16; i += 256) {
            int r = i >> 4, c4 = (i & 15) << 2;
            float4 v = make_float4(0.f, 0.f, 0.f, 0.f);
            if (r < NREAL) v = *(const float4*)&B[(size_t)r * KK + k0 + c4];
            int o = r * LDK + c4;
            Bs[o] = f2b(v.x); Bs[o + 1] = f2b(v.y);
            Bs[o + 2] = f2b(v.z); Bs[o + 3] = f2b(v.w);
        }
        __syncthreads();

        for (int ks = 0; ks < BK; ks += 32) {
            int kc = ks + lkg * 8;
            int row = wave * 16 + lrow;
            shortx8 a = *(const shortx8*)&As[row * LDK + kc];
#pragma unroll
            for (int nt = 0; nt < NT; nt++) {
                shortx8 b = *(const shortx8*)&Bs[(nt * 16 + lrow) * LDK + kc];
                acc[nt] = __builtin_amdgcn_mfma_f32_16x16x32_bf16(a, b, acc[nt], 0, 0, 0);
            }
        }
    }
#pragma unroll
    for (int nt = 0; nt < NT; nt++)
#pragma unroll
        for (int r = 0; r < 4; r++) {
            int row = bm + wave * 16 + lkg * 4 + r;
            int col = nt * 16 + lrow;
            if (row < M && col < NREAL)
                Cb[(size_t)row * NREAL + col] = f2b(acc[nt][r]);
        }
}

// ---------------------------------------------------------------------------
// Attention coefficients from bf16 h
// ---------------------------------------------------------------------------
__global__ void att1_kernel(const unsigned short* __restrict__ h1b,
                            const float* __restrict__ att_src,
                            const float* __restrict__ att_dst,
                            float* __restrict__ a_src, float* __restrict__ a_dst,
                            int N) {
    int i = blockIdx.x * blockDim.x + threadIdx.x;
    if (i >= N * 4) return;
    int h = i & 3;
    const ushort4* hp = (const ushort4*)(h1b + (size_t)i * 32);
    const float4* as = (const float4*)(att_src + h * 32);
    const float4* ad = (const float4*)(att_dst + h * 32);
    float ssum = 0.f, dsum = 0.f;
#pragma unroll
    for (int j = 0; j < 8; j++) {
        ushort4 hv = hp[j];
        float4 av = as[j], dv = ad[j];
        float x0 = b2f(hv.x), x1 = b2f(hv.y), x2 = b2f(hv.z), x3 = b2f(hv.w);
        ssum += x0 * av.x + x1 * av.y + x2 * av.z + x3 * av.w;
        dsum += x0 * dv.x + x1 * dv.y + x2 * dv.z + x3 * dv.w;
    }
    a_src[i] = ssum;
    a_dst[i] = dsum;
}

__global__ void att2_kernel(const unsigned short* __restrict__ h2b,
                            const float* __restrict__ att_src,
                            const float* __restrict__ att_dst,
                            float* __restrict__ a_src, float* __restrict__ a_dst,
                            int N) {
    int n = blockIdx.x * blockDim.x + threadIdx.x;
    if (n >= N) return;
    const ushort4* hp = (const ushort4*)(h2b + (size_t)n * 40);
    const float4* as = (const float4*)att_src;
    const float4* ad = (const float4*)att_dst;
    float ssum = 0.f, dsum = 0.f;
#pragma unroll
    for (int j = 0; j < 10; j++) {
        ushort4 hv = hp[j];
        float4 av = as[j], dv = ad[j];
        float x0 = b2f(hv.x), x1 = b2f(hv.y), x2 = b2f(hv.z), x3 = b2f(hv.w);
        ssum += x0 * av.x + x1 * av.y + x2 * av.z + x3 * av.w;
        dsum += x0 * dv.x + x1 * dv.y + x2 * dv.z + x3 * dv.w;
    }
    a_src[n] = ssum;
    a_dst[n] = dsum;
}

// ---------------------------------------------------------------------------
// Aggregation layer 1: one WAVE per node. v4: shfl coeff phase (zero VMEM
// for weights) + dwordx4 gather: 16 lanes x ushort8 = one 256B node row,
// 4 edges per wave-instruction. Gather VMEM instrs halved vs v2, shfl halved.
// Lane layout: eg = lane>>4 (edge slot), fpos = lane&15 (feature block of 8).
// ---------------------------------------------------------------------------
__global__ __launch_bounds__(256) void agg1_kernel(
    const unsigned short* __restrict__ h1b, const float* __restrict__ a_src,
    const float* __restrict__ a_dst, const int* __restrict__ rowptr,
    const int* __restrict__ csr_src, const float* __restrict__ b1,
    unsigned short* __restrict__ zb, int N) {
    int wave = threadIdx.x >> 6, lane = threadIdx.x & 63;
    int n = blockIdx.x * 4 + wave;
    if (n >= N) return;
    int eg = lane >> 4;        // edge-slot group 0..3
    int fpos = lane & 15;      // feature block: feats fpos*8 .. fpos*8+7
    int hd = fpos >> 2;        // head of this feature block ((fpos*8)>>5)
    float adn = a_dst[n * 4 + (lane & 3)];
    int beg = rowptr[n], deg = rowptr[n + 1] - beg;

    float acc[8] = {0.f, 0.f, 0.f, 0.f, 0.f, 0.f, 0.f, 0.f};
    float den = 0.f;
    for (int c0 = 0; c0 < deg; c0 += 16) {
        // coeff phase: 4 lanes per edge compute per-head logits, 16 edges
        int idx = c0 + (lane >> 2);
        int s_e = (idx < deg) ? csr_src[beg + idx] : 0;
        float l = a_src[(s_e << 2) + (lane & 3)] + adn;
        l = l > 0.f ? l : NEG_SLOPE * l;
        float w_e = (idx < deg) ? __expf(l) : 0.f;  // zero-pad dead edges
        int cnt = min(16, deg - c0);
        int s4[4]; float w4[4]; shortx8 v4[4];
#pragma unroll
        for (int q = 0; q < 4; q++) {
            if (q * 4 < cnt) {
                int el = (q << 2) + eg;
                s4[q] = __shfl(s_e, el << 2);
                w4[q] = __shfl(w_e, (el << 2) + hd);
            }
        }
#pragma unroll
        for (int q = 0; q < 4; q++) {
            if (q * 4 < cnt)
                v4[q] = *(const shortx8*)&h1b[(size_t)s4[q] * 128 + fpos * 8];
        }
#pragma unroll
        for (int q = 0; q < 4; q++) {
            if (q * 4 < cnt) {
                float w = w4[q];
                den += w;
#pragma unroll
                for (int j = 0; j < 8; j++)
                    acc[j] += w * b2f((unsigned short)v4[q][j]);
            }
        }
    }
    // combine the 4 edge-slot partials (groups differ in lane>>4)
#pragma unroll
    for (int j = 0; j < 8; j++) {
        acc[j] += __shfl_xor(acc[j], 16);
        acc[j] += __shfl_xor(acc[j], 32);
    }
    den += __shfl_xor(den, 16);
    den += __shfl_xor(den, 32);
    if (lane < 16) {
        float inv = 1.f / den;
        float4 bb0 = *(const float4*)&b1[fpos * 8];
        float4 bb1 = *(const float4*)&b1[fpos * 8 + 4];
        shortx8 r;
        r[0] = (short)f2b(fmaxf(acc[0] * inv + bb0.x, 0.f));
        r[1] = (short)f2b(fmaxf(acc[1] * inv + bb0.y, 0.f));
        r[2] = (short)f2b(fmaxf(acc[2] * inv + bb0.z, 0.f));
        r[3] = (short)f2b(fmaxf(acc[3] * inv + bb0.w, 0.f));
        r[4] = (short)f2b(fmaxf(acc[4] * inv + bb1.x, 0.f));
        r[5] = (short)f2b(fmaxf(acc[5] * inv + bb1.y, 0.f));
        r[6] = (short)f2b(fmaxf(acc[6] * inv + bb1.z, 0.f));
        r[7] = (short)f2b(fmaxf(acc[7] * inv + bb1.w, 0.f));
        *(shortx8*)&zb[(size_t)n * 128 + fpos * 8] = r;
    }
}

// ---------------------------------------------------------------------------
// Aggregation layer 2: one wave per node, H=1, D=40 (80B rows). v4: 3 edges
// per wave-instruction (20 lanes x ushort2 each), coeff phase covers 48 edges
// so nearly every node needs exactly one phase.
// ---------------------------------------------------------------------------
__global__ __launch_bounds__(256) void agg2_kernel(
    const unsigned short* __restrict__ h2b, const float* __restrict__ a_src,
    const float* __restrict__ a_dst, const int* __restrict__ rowptr,
    const int* __restrict__ csr_src, const float* __restrict__ b2,
    float* __restrict__ out, int N) {
    int wave = threadIdx.x >> 6, lane = threadIdx.x & 63;
    int n = blockIdx.x * 4 + wave;
    if (n >= N) return;
    int eg = (lane >= 40) ? 2 : (lane >= 20 ? 1 : 0);  // edge-slot 0..2
    int fp = lane - eg * 20;                            // 0..19 (lanes 60-63: 20-23)
    bool act = fp < 20;
    float adn = a_dst[n];
    int beg = rowptr[n], deg = rowptr[n + 1] - beg;

    float2 acc = {0.f, 0.f};
    float den = 0.f;
    for (int c0 = 0; c0 < deg; c0 += 48) {
        int idx = c0 + lane;
        bool cv = (lane < 48) && (idx < deg);
        int s_e = cv ? csr_src[beg + idx] : 0;
        float l = a_src[s_e] + adn;
        l = l > 0.f ? l : NEG_SLOPE * l;
        float w_e = cv ? __expf(l) : 0.f;   // zero-pad dead edges
        int cnt = min(48, deg - c0);
#pragma unroll
        for (int qq = 0; qq < 4; qq++) {
            if (qq * 12 < cnt) {
                int s4[4]; float w4[4]; ushort2 v4[4];
#pragma unroll
                for (int q = 0; q < 4; q++) {
                    int el = qq * 12 + q * 3 + eg;
                    s4[q] = __shfl(s_e, el);
                    w4[q] = __shfl(w_e, el);
                }
#pragma unroll
                for (int q = 0; q < 4; q++) {
                    if (act)
                        v4[q] = *(const ushort2*)&h2b[(size_t)s4[q] * 40 + fp * 2];
                }
#pragma unroll
                for (int q = 0; q < 4; q++) {
                    float w = w4[q];
                    den += w;
                    if (act) {
                        acc.x += w * b2f(v4[q].x);
                        acc.y += w * b2f(v4[q].y);
                    }
                }
            }
        }
    }
    // combine 3 edge-slot partials: lanes {fp, fp+20, fp+40}
    float a1x = __shfl(acc.x, fp + 20), a2x = __shfl(acc.x, fp + 40);
    float a1y = __shfl(acc.y, fp + 20), a2y = __shfl(acc.y, fp + 40);
    float d1  = __shfl(den,  fp + 20), d2  = __shfl(den,  fp + 40);
    if (lane < 20) {
        float sx = acc.x + a1x + a2x;
        float sy = acc.y + a1y + a2y;
        float dtot = den + d1 + d2;
        float inv = 1.f / dtot;
        float2 bb = *(const float2*)&b2[fp * 2];
        float2 o;
        o.x = sx * inv + bb.x;
        o.y = sy * inv + bb.y;
        *(float2*)&out[(size_t)n * 40 + fp * 2] = o;
    }
}

// ---------------------------------------------------------------------------
extern "C" void kernel_launch(void* const* d_in, const int* in_sizes, int n_in,
                              void* d_out, int out_size, void* d_ws, size_t ws_size,
                              hipStream_t stream) {
    const float* x        = (const float*)d_in[0];
    const int*   ei       = (const int*)d_in[1];
    const float* W1       = (const float*)d_in[2];
    const float* att_src1 = (const float*)d_in[3];
    const float* att_dst1 = (const float*)d_in[4];
    const float* b1       = (const float*)d_in[5];
    const float* W2       = (const float*)d_in[6];
    const float* att_src2 = (const float*)d_in[7];
    const float* att_dst2 = (const float*)d_in[8];
    const float* b2       = (const float*)d_in[9];
    float* out = (float*)d_out;

    const int N  = N_NODES;
    const int E0 = in_sizes[1] / 2;
    const int E  = E0 + N;
    const int NBLK = (E + BIN_CHUNK - 1) / BIN_CHUNK;

    char* ws = (char*)d_ws;
    unsigned short* h1b = (unsigned short*)(ws + 0);          // 12,800,000
    unsigned short* zb  = (unsigned short*)(ws + 12800000);   // 12,800,000
    unsigned short* h2b = (unsigned short*)(ws + 25600000);   //  4,000,000
    float* a_src1 = (float*)(ws + 29600000);                  //    800,000
    float* a_dst1 = (float*)(ws + 30400000);                  //    800,000
    float* a_src2 = (float*)(ws + 31200000);                  //    200,000
    float* a_dst2 = (float*)(ws + 31400000);                  //    200,000
    int*   rowptr = (int*)(ws + 31600000);                    //    200,004
    int*   bhist  = (int*)(ws + 31800192);                    //        784
    int*   bbase  = (int*)(ws + 31801088);                    //        788
    int*   bcursor= (int*)(ws + 31801984);                    //        784
    unsigned int* ebuf = (unsigned int*)(ws + 31802880);      //  3,400,000
    int*   csr_src= (int*)(ws + 35202880);                    //  3,400,000
    // total ~38.6 MB

    hipMemsetAsync(bhist, 0, NB * sizeof(int), stream);

    bucket_hist_kernel<<<NBLK, 256, 0, stream>>>(ei, E0, E, bhist);
    bucket_scan_kernel<<<1, 256, 0, stream>>>(bhist, bbase, bcursor, rowptr, E);
    bin_kernel<<<NBLK, 256, 0, stream>>>(ei, E0, E, bcursor, ebuf);
    build_kernel<<<NB, 256, 0, stream>>>(ebuf, bbase, rowptr, csr_src);

    // layer 1: h1b = bf16(x @ W1^T)
    gemm_bf16_kernel<64, 128, 128, 256, float>
        <<<(N + 63) / 64, 256, 0, stream>>>(x, W1, h1b, N);
    att1_kernel<<<(N * 4 + 255) / 256, 256, 0, stream>>>(h1b, att_src1, att_dst1, a_src1, a_dst1, N);
    agg1_kernel<<<(N + 3) / 4, 256, 0, stream>>>(h1b, a_src1, a_dst1, rowptr, csr_src, b1, zb, N);

    // layer 2: h2b = bf16(zb @ W2^T)
    gemm_bf16_kernel<64, 48, 40, 128, unsigned short>
        <<<(N + 63) / 64, 256, 0, stream>>>(zb, W2, h2b, N);
    att2_kernel<<<(N + 255) / 256, 256, 0, stream>>>(h2b, att_src2, att_dst2, a_src2, a_dst2, N);
    agg2_kernel<<<(N + 3) / 4, 256, 0, stream>>>(h2b, a_src2, a_dst2, rowptr, csr_src, b2, out, N);
}

// Round 4
// 243.342 us; speedup vs baseline: 1.1234x; 1.0028x over previous
//
#include <hip/hip_runtime.h>
#include <hip/hip_bf16.h>
#include <cstdint>
#include <cstddef>

#define N_NODES 50000
#define NEG_SLOPE 0.2f
#define NB 196            // buckets of 256 nodes: (50000+255)/256
#define BIN_CHUNK 8192    // edges per block in hist/bin kernels
#define SLICE_MAX 14336   // LDS slice capacity (mean ~4345, 3.3x headroom)

typedef float floatx4 __attribute__((ext_vector_type(4)));
typedef short shortx8 __attribute__((ext_vector_type(8)));

// ---- fp32 <-> bf16 helpers (RNE) --------------------------------------------
__device__ __forceinline__ unsigned short f2b(float f) {
    union { float f; unsigned u; } v; v.f = f;
    unsigned u = v.u;
    return (unsigned short)((u + 0x7FFFu + ((u >> 16) & 1u)) >> 16);
}
__device__ __forceinline__ float b2f(unsigned short b) {
    union { unsigned u; float f; } v; v.u = ((unsigned)b) << 16;
    return v.f;
}

// ---------------------------------------------------------------------------
// CSR build, bucketed multisplit.
// K1: bucket histogram (LDS per block, 196 global atomics per block)
// ---------------------------------------------------------------------------
__global__ __launch_bounds__(256) void bucket_hist_kernel(
    const int* __restrict__ ei, int E0, int E, int* __restrict__ bhist) {
    __shared__ int h[NB];
    int t = threadIdx.x;
    for (int i = t; i < NB; i += 256) h[i] = 0;
    __syncthreads();
    int base = blockIdx.x * BIN_CHUNK;
    int end = min(base + BIN_CHUNK, E);
    for (int e = base + t; e < end; e += 256) {
        int d = (e < E0) ? ei[E0 + e] : (e - E0);
        atomicAdd(&h[d >> 8], 1);
    }
    __syncthreads();
    for (int i = t; i < NB; i += 256)
        if (h[i]) atomicAdd(&bhist[i], h[i]);
}

// K2: scan 196 bucket counts -> bbase[NB+1], init bcursor, rowptr[N]=E
__global__ __launch_bounds__(256) void bucket_scan_kernel(
    const int* __restrict__ bhist, int* __restrict__ bbase,
    int* __restrict__ bcursor, int* __restrict__ rowptr, int E) {
    __shared__ int buf[256];
    int t = threadIdx.x;
    int v = (t < NB) ? bhist[t] : 0;
    int x = v;
    for (int off = 1; off < 256; off <<= 1) {
        buf[t] = x; __syncthreads();
        int y = (t >= off) ? buf[t - off] : 0;
        __syncthreads();
        x += y;
    }
    if (t < NB) {
        bbase[t] = x - v;      // exclusive
        bcursor[t] = x - v;
    }
    if (t == NB - 1) bbase[NB] = x;
    if (t == 0) rowptr[N_NODES] = E;
}

// K3: bin edges into bucket regions, packed src|(dst&255)<<16, burst writes
__global__ __launch_bounds__(256) void bin_kernel(
    const int* __restrict__ ei, int E0, int E,
    int* __restrict__ bcursor, unsigned int* __restrict__ ebuf) {
    __shared__ int h[NB];
    __shared__ int gbase[NB];
    int t = threadIdx.x;
    for (int i = t; i < NB; i += 256) h[i] = 0;
    __syncthreads();
    int base = blockIdx.x * BIN_CHUNK;
    int end = min(base + BIN_CHUNK, E);
    // pass 1: local histogram
    for (int e = base + t; e < end; e += 256) {
        int d = (e < E0) ? ei[E0 + e] : (e - E0);
        atomicAdd(&h[d >> 8], 1);
    }
    __syncthreads();
    // reserve global bursts
    for (int i = t; i < NB; i += 256) {
        int c = h[i];
        gbase[i] = c ? atomicAdd(&bcursor[i], c) : 0;
        h[i] = 0;  // reuse as local cursor
    }
    __syncthreads();
    // pass 2: re-read (L2-hot) and place
    for (int e = base + t; e < end; e += 256) {
        int s, d;
        if (e < E0) { s = ei[e]; d = ei[E0 + e]; }
        else        { s = e - E0; d = e - E0; }
        int b = d >> 8;
        int off = atomicAdd(&h[b], 1);
        ebuf[gbase[b] + off] = (unsigned)s | ((unsigned)(d & 255) << 16);
    }
}

// K4: one block per bucket: local deg-hist -> rowptr, LDS-staged CSR slice,
// fully-coalesced slice write.
__global__ __launch_bounds__(256) void build_kernel(
    const unsigned int* __restrict__ ebuf, const int* __restrict__ bbase,
    int* __restrict__ rowptr, int* __restrict__ csr_src) {
    __shared__ int h[256];
    __shared__ int lrp[257];
    __shared__ int stag[SLICE_MAX];
    int b = blockIdx.x, t = threadIdx.x;
    int e0 = bbase[b], e1 = bbase[b + 1];
    int cnt = e1 - e0;
    int n0 = b << 8;
    h[t] = 0;
    __syncthreads();
    // pass A: per-node degree histogram
    for (int i = t; i < cnt; i += 256)
        atomicAdd(&h[ebuf[e0 + i] >> 16], 1);
    __syncthreads();
    // scan 256 -> exclusive lrp
    int v = h[t], x = v;
    __shared__ int buf[256];
    for (int off = 1; off < 256; off <<= 1) {
        buf[t] = x; __syncthreads();
        int y = (t >= off) ? buf[t - off] : 0;
        __syncthreads();
        x += y;
    }
    lrp[t] = x - v;
    if (t == 255) lrp[256] = x;
    h[t] = 0;  // reuse as fill counters
    __syncthreads();
    int n = n0 + t;
    if (n < N_NODES) rowptr[n] = e0 + lrp[t];
    // pass B: place srcs into LDS slice
    for (int i = t; i < cnt; i += 256) {
        unsigned int v2 = ebuf[e0 + i];
        int dloc = v2 >> 16;
        int off = atomicAdd(&h[dloc], 1);
        stag[lrp[dloc] + off] = (int)(v2 & 0xFFFFu);
    }
    __syncthreads();
    // pass C: coalesced slice write-out
    for (int i = t; i < cnt; i += 256) csr_src[e0 + i] = stag[i];
}

// ---------------------------------------------------------------------------
// Single-bf16 MFMA GEMM:  Cb[M,NREAL](bf16) = A[M,KK] x B[NREAL,KK]^T
// ---------------------------------------------------------------------------
template <int BM, int BN, int NREAL, int KK, typename InT>
__global__ __launch_bounds__(256) void gemm_bf16_kernel(
    const InT* __restrict__ A, const float* __restrict__ B,
    unsigned short* __restrict__ Cb, int M) {
    const int BK = 64, LDK = 72;
    const int NT = BN / 16;
    __shared__ unsigned short As[BM * LDK];
    __shared__ unsigned short Bs[BN * LDK];
    const int t = threadIdx.x;
    const int wave = t >> 6, lane = t & 63;
    const int lrow = lane & 15, lkg = lane >> 4;
    const int bm = blockIdx.x * BM;

    floatx4 acc[NT] = {};

    for (int k0 = 0; k0 < KK; k0 += BK) {
        __syncthreads();
        if constexpr (sizeof(InT) == 4) {
            for (int i = t; i < BM * 16; i += 256) {
                int r = i >> 4, c4 = (i & 15) << 2;
                int gr = bm + r;
                float4 v = make_float4(0.f, 0.f, 0.f, 0.f);
                if (gr < M) v = *(const float4*)&A[(size_t)gr * KK + k0 + c4];
                int o = r * LDK + c4;
                As[o] = f2b(v.x); As[o + 1] = f2b(v.y);
                As[o + 2] = f2b(v.z); As[o + 3] = f2b(v.w);
            }
        } else {
            for (int i = t; i < BM * 8; i += 256) {
                int r = i >> 3, c8 = (i & 7) << 3;
                int gr = bm + r;
                shortx8 v = {};
                if (gr < M) v = *(const shortx8*)&A[(size_t)gr * KK + k0 + c8];
                *(shortx8*)&As[r * LDK + c8] = v;
            }
        }
        for (int i = t; i < BN * 16; i += 256) {
            int r = i >> 4, c4 = (i & 15) << 2;
            float4 v = make_float4(0.f, 0.f, 0.f, 0.f);
            if (r < NREAL) v = *(const float4*)&B[(size_t)r * KK + k0 + c4];
            int o = r * LDK + c4;
            Bs[o] = f2b(v.x); Bs[o + 1] = f2b(v.y);
            Bs[o + 2] = f2b(v.z); Bs[o + 3] = f2b(v.w);
        }
        __syncthreads();

        for (int ks = 0; ks < BK; ks += 32) {
            int kc = ks + lkg * 8;
            int row = wave * 16 + lrow;
            shortx8 a = *(const shortx8*)&As[row * LDK + kc];
#pragma unroll
            for (int nt = 0; nt < NT; nt++) {
                shortx8 b = *(const shortx8*)&Bs[(nt * 16 + lrow) * LDK + kc];
                acc[nt] = __builtin_amdgcn_mfma_f32_16x16x32_bf16(a, b, acc[nt], 0, 0, 0);
            }
        }
    }
#pragma unroll
    for (int nt = 0; nt < NT; nt++)
#pragma unroll
        for (int r = 0; r < 4; r++) {
            int row = bm + wave * 16 + lkg * 4 + r;
            int col = nt * 16 + lrow;
            if (row < M && col < NREAL)
                Cb[(size_t)row * NREAL + col] = f2b(acc[nt][r]);
        }
}

// ---------------------------------------------------------------------------
// Attention coefficients from bf16 h
// ---------------------------------------------------------------------------
__global__ void att1_kernel(const unsigned short* __restrict__ h1b,
                            const float* __restrict__ att_src,
                            const float* __restrict__ att_dst,
                            float* __restrict__ a_src, float* __restrict__ a_dst,
                            int N) {
    int i = blockIdx.x * blockDim.x + threadIdx.x;
    if (i >= N * 4) return;
    int h = i & 3;
    const ushort4* hp = (const ushort4*)(h1b + (size_t)i * 32);
    const float4* as = (const float4*)(att_src + h * 32);
    const float4* ad = (const float4*)(att_dst + h * 32);
    float ssum = 0.f, dsum = 0.f;
#pragma unroll
    for (int j = 0; j < 8; j++) {
        ushort4 hv = hp[j];
        float4 av = as[j], dv = ad[j];
        float x0 = b2f(hv.x), x1 = b2f(hv.y), x2 = b2f(hv.z), x3 = b2f(hv.w);
        ssum += x0 * av.x + x1 * av.y + x2 * av.z + x3 * av.w;
        dsum += x0 * dv.x + x1 * dv.y + x2 * dv.z + x3 * dv.w;
    }
    a_src[i] = ssum;
    a_dst[i] = dsum;
}

__global__ void att2_kernel(const unsigned short* __restrict__ h2b,
                            const float* __restrict__ att_src,
                            const float* __restrict__ att_dst,
                            float* __restrict__ a_src, float* __restrict__ a_dst,
                            int N) {
    int n = blockIdx.x * blockDim.x + threadIdx.x;
    if (n >= N) return;
    const ushort4* hp = (const ushort4*)(h2b + (size_t)n * 40);
    const float4* as = (const float4*)att_src;
    const float4* ad = (const float4*)att_dst;
    float ssum = 0.f, dsum = 0.f;
#pragma unroll
    for (int j = 0; j < 10; j++) {
        ushort4 hv = hp[j];
        float4 av = as[j], dv = ad[j];
        float x0 = b2f(hv.x), x1 = b2f(hv.y), x2 = b2f(hv.z), x3 = b2f(hv.w);
        ssum += x0 * av.x + x1 * av.y + x2 * av.z + x3 * av.w;
        dsum += x0 * dv.x + x1 * dv.y + x2 * dv.z + x3 * dv.w;
    }
    a_src[n] = ssum;
    a_dst[n] = dsum;
}

// ---------------------------------------------------------------------------
// Aggregation layer 1: one WAVE per node. v5: v4's dwordx4 gather (4 edges
// per wave-instruction) + 2-stage software pipeline across 16-edge chunks:
// while chunk i's gathers are in flight, chunk i+1's csr_src + a_src loads
// issue and its expf computes. Accumulation order identical to v4.
// ---------------------------------------------------------------------------
__global__ __launch_bounds__(256) void agg1_kernel(
    const unsigned short* __restrict__ h1b, const float* __restrict__ a_src,
    const float* __restrict__ a_dst, const int* __restrict__ rowptr,
    const int* __restrict__ csr_src, const float* __restrict__ b1,
    unsigned short* __restrict__ zb, int N) {
    int wave = threadIdx.x >> 6, lane = threadIdx.x & 63;
    int n = blockIdx.x * 4 + wave;
    if (n >= N) return;
    int eg = lane >> 4;        // edge-slot group 0..3
    int fpos = lane & 15;      // feature block: feats fpos*8 .. fpos*8+7
    int hd = fpos >> 2;        // head of this feature block
    int lidx = lane >> 2;      // edge slot 0..15 in coeff phase
    int lh = lane & 3;         // head in coeff phase
    float adn = a_dst[n * 4 + lh];
    int beg = rowptr[n], deg = rowptr[n + 1] - beg;

    float acc[8] = {0.f, 0.f, 0.f, 0.f, 0.f, 0.f, 0.f, 0.f};
    float den = 0.f;

    // prologue: coeff inputs for chunk 0
    int s_e = (lidx < deg) ? csr_src[beg + lidx] : 0;
    float asv = a_src[(s_e << 2) + lh];

    for (int c0 = 0; c0 < deg; c0 += 16) {
        // finish coeff for current chunk
        float l = asv + adn;
        l = l > 0.f ? l : NEG_SLOPE * l;
        float w_e = (c0 + lidx < deg) ? __expf(l) : 0.f;  // zero-pad dead edges
        int cnt = min(16, deg - c0);
        // broadcast (s,w) per edge group
        int s4[4]; float w4[4]; shortx8 v4[4];
#pragma unroll
        for (int q = 0; q < 4; q++) {
            int el = (q << 2) + eg;
            s4[q] = __shfl(s_e, el << 2);
            w4[q] = __shfl(w_e, (el << 2) + hd);
        }
        // issue gathers for current chunk
#pragma unroll
        for (int q = 0; q < 4; q++) {
            if (q * 4 < cnt)
                v4[q] = *(const shortx8*)&h1b[(size_t)s4[q] * 128 + fpos * 8];
        }
        // prefetch next chunk's coeff inputs (overlaps gather latency)
        int nidx = c0 + 16 + lidx;
        int s_n = (nidx < deg) ? csr_src[beg + nidx] : 0;
        float asn = a_src[(s_n << 2) + lh];
        // consume gathers
#pragma unroll
        for (int q = 0; q < 4; q++) {
            if (q * 4 < cnt) {
                float w = w4[q];
                den += w;
#pragma unroll
                for (int j = 0; j < 8; j++)
                    acc[j] += w * b2f((unsigned short)v4[q][j]);
            }
        }
        s_e = s_n; asv = asn;
    }
    // combine the 4 edge-slot partials (groups differ in lane>>4)
#pragma unroll
    for (int j = 0; j < 8; j++) {
        acc[j] += __shfl_xor(acc[j], 16);
        acc[j] += __shfl_xor(acc[j], 32);
    }
    den += __shfl_xor(den, 16);
    den += __shfl_xor(den, 32);
    if (lane < 16) {
        float inv = 1.f / den;
        float4 bb0 = *(const float4*)&b1[fpos * 8];
        float4 bb1 = *(const float4*)&b1[fpos * 8 + 4];
        shortx8 r;
        r[0] = (short)f2b(fmaxf(acc[0] * inv + bb0.x, 0.f));
        r[1] = (short)f2b(fmaxf(acc[1] * inv + bb0.y, 0.f));
        r[2] = (short)f2b(fmaxf(acc[2] * inv + bb0.z, 0.f));
        r[3] = (short)f2b(fmaxf(acc[3] * inv + bb0.w, 0.f));
        r[4] = (short)f2b(fmaxf(acc[4] * inv + bb1.x, 0.f));
        r[5] = (short)f2b(fmaxf(acc[5] * inv + bb1.y, 0.f));
        r[6] = (short)f2b(fmaxf(acc[6] * inv + bb1.z, 0.f));
        r[7] = (short)f2b(fmaxf(acc[7] * inv + bb1.w, 0.f));
        *(shortx8*)&zb[(size_t)n * 128 + fpos * 8] = r;
    }
}

// ---------------------------------------------------------------------------
// Aggregation layer 2: one wave per node, H=1, D=40 (80B rows). v4: 3 edges
// per wave-instruction (20 lanes x ushort2 each), coeff phase covers 48 edges
// so nearly every node needs exactly one phase.
// ---------------------------------------------------------------------------
__global__ __launch_bounds__(256) void agg2_kernel(
    const unsigned short* __restrict__ h2b, const float* __restrict__ a_src,
    const float* __restrict__ a_dst, const int* __restrict__ rowptr,
    const int* __restrict__ csr_src, const float* __restrict__ b2,
    float* __restrict__ out, int N) {
    int wave = threadIdx.x >> 6, lane = threadIdx.x & 63;
    int n = blockIdx.x * 4 + wave;
    if (n >= N) return;
    int eg = (lane >= 40) ? 2 : (lane >= 20 ? 1 : 0);  // edge-slot 0..2
    int fp = lane - eg * 20;                            // 0..19 (lanes 60-63: 20-23)
    bool act = fp < 20;
    float adn = a_dst[n];
    int beg = rowptr[n], deg = rowptr[n + 1] - beg;

    float2 acc = {0.f, 0.f};
    float den = 0.f;
    for (int c0 = 0; c0 < deg; c0 += 48) {
        int idx = c0 + lane;
        bool cv = (lane < 48) && (idx < deg);
        int s_e = cv ? csr_src[beg + idx] : 0;
        float l = a_src[s_e] + adn;
        l = l > 0.f ? l : NEG_SLOPE * l;
        float w_e = cv ? __expf(l) : 0.f;   // zero-pad dead edges
        int cnt = min(48, deg - c0);
#pragma unroll
        for (int qq = 0; qq < 4; qq++) {
            if (qq * 12 < cnt) {
                int s4[4]; float w4[4]; ushort2 v4[4];
#pragma unroll
                for (int q = 0; q < 4; q++) {
                    int el = qq * 12 + q * 3 + eg;
                    s4[q] = __shfl(s_e, el);
                    w4[q] = __shfl(w_e, el);
                }
#pragma unroll
                for (int q = 0; q < 4; q++) {
                    if (act)
                        v4[q] = *(const ushort2*)&h2b[(size_t)s4[q] * 40 + fp * 2];
                }
#pragma unroll
                for (int q = 0; q < 4; q++) {
                    float w = w4[q];
                    den += w;
                    if (act) {
                        acc.x += w * b2f(v4[q].x);
                        acc.y += w * b2f(v4[q].y);
                    }
                }
            }
        }
    }
    // combine 3 edge-slot partials: lanes {fp, fp+20, fp+40}
    float a1x = __shfl(acc.x, fp + 20), a2x = __shfl(acc.x, fp + 40);
    float a1y = __shfl(acc.y, fp + 20), a2y = __shfl(acc.y, fp + 40);
    float d1  = __shfl(den,  fp + 20), d2  = __shfl(den,  fp + 40);
    if (lane < 20) {
        float sx = acc.x + a1x + a2x;
        float sy = acc.y + a1y + a2y;
        float dtot = den + d1 + d2;
        float inv = 1.f / dtot;
        float2 bb = *(const float2*)&b2[fp * 2];
        float2 o;
        o.x = sx * inv + bb.x;
        o.y = sy * inv + bb.y;
        *(float2*)&out[(size_t)n * 40 + fp * 2] = o;
    }
}

// ---------------------------------------------------------------------------
extern "C" void kernel_launch(void* const* d_in, const int* in_sizes, int n_in,
                              void* d_out, int out_size, void* d_ws, size_t ws_size,
                              hipStream_t stream) {
    const float* x        = (const float*)d_in[0];
    const int*   ei       = (const int*)d_in[1];
    const float* W1       = (const float*)d_in[2];
    const float* att_src1 = (const float*)d_in[3];
    const float* att_dst1 = (const float*)d_in[4];
    const float* b1       = (const float*)d_in[5];
    const float* W2       = (const float*)d_in[6];
    const float* att_src2 = (const float*)d_in[7];
    const float* att_dst2 = (const float*)d_in[8];
    const float* b2       = (const float*)d_in[9];
    float* out = (float*)d_out;

    const int N  = N_NODES;
    const int E0 = in_sizes[1] / 2;
    const int E  = E0 + N;
    const int NBLK = (E + BIN_CHUNK - 1) / BIN_CHUNK;

    char* ws = (char*)d_ws;
    unsigned short* h1b = (unsigned short*)(ws + 0);          // 12,800,000
    unsigned short* zb  = (unsigned short*)(ws + 12800000);   // 12,800,000
    unsigned short* h2b = (unsigned short*)(ws + 25600000);   //  4,000,000
    float* a_src1 = (float*)(ws + 29600000);                  //    800,000
    float* a_dst1 = (float*)(ws + 30400000);                  //    800,000
    float* a_src2 = (float*)(ws + 31200000);                  //    200,000
    float* a_dst2 = (float*)(ws + 31400000);                  //    200,000
    int*   rowptr = (int*)(ws + 31600000);                    //    200,004
    int*   bhist  = (int*)(ws + 31800192);                    //        784
    int*   bbase  = (int*)(ws + 31801088);                    //        788
    int*   bcursor= (int*)(ws + 31801984);                    //        784
    unsigned int* ebuf = (unsigned int*)(ws + 31802880);      //  3,400,000
    int*   csr_src= (int*)(ws + 35202880);                    //  3,400,000
    // total ~38.6 MB

    hipMemsetAsync(bhist, 0, NB * sizeof(int), stream);

    bucket_hist_kernel<<<NBLK, 256, 0, stream>>>(ei, E0, E, bhist);
    bucket_scan_kernel<<<1, 256, 0, stream>>>(bhist, bbase, bcursor, rowptr, E);
    bin_kernel<<<NBLK, 256, 0, stream>>>(ei, E0, E, bcursor, ebuf);
    build_kernel<<<NB, 256, 0, stream>>>(ebuf, bbase, rowptr, csr_src);

    // layer 1: h1b = bf16(x @ W1^T)
    gemm_bf16_kernel<64, 128, 128, 256, float>
        <<<(N + 63) / 64, 256, 0, stream>>>(x, W1, h1b, N);
    att1_kernel<<<(N * 4 + 255) / 256, 256, 0, stream>>>(h1b, att_src1, att_dst1, a_src1, a_dst1, N);
    agg1_kernel<<<(N + 3) / 4, 256, 0, stream>>>(h1b, a_src1, a_dst1, rowptr, csr_src, b1, zb, N);

    // layer 2: h2b = bf16(zb @ W2^T)
    gemm_bf16_kernel<64, 48, 40, 128, unsigned short>
        <<<(N + 63) / 64, 256, 0, stream>>>(zb, W2, h2b, N);
    att2_kernel<<<(N + 255) / 256, 256, 0, stream>>>(h2b, att_src2, att_dst2, a_src2, a_dst2, N);
    agg2_kernel<<<(N + 3) / 4, 256, 0, stream>>>(h2b, a_src2, a_dst2, rowptr, csr_src, b2, out, N);
}

// Round 5
// 236.866 us; speedup vs baseline: 1.1541x; 1.0273x over previous
//
#include <hip/hip_runtime.h>
#include <hip/hip_bf16.h>
#include <cstdint>
#include <cstddef>

#define N_NODES 50000
#define NEG_SLOPE 0.2f
#define NB 196            // buckets of 256 nodes: (50000+255)/256
#define BIN_CHUNK 8192    // edges per block in hist/bin kernels
#define SLICE_MAX 14336   // LDS slice capacity (mean ~4345, 3.3x headroom)

typedef float floatx4 __attribute__((ext_vector_type(4)));
typedef short shortx8 __attribute__((ext_vector_type(8)));

// ---- fp32 <-> bf16 helpers (RNE) --------------------------------------------
__device__ __forceinline__ unsigned short f2b(float f) {
    union { float f; unsigned u; } v; v.f = f;
    unsigned u = v.u;
    return (unsigned short)((u + 0x7FFFu + ((u >> 16) & 1u)) >> 16);
}
__device__ __forceinline__ float b2f(unsigned short b) {
    union { unsigned u; float f; } v; v.u = ((unsigned)b) << 16;
    return v.f;
}

// ---------------------------------------------------------------------------
// CSR build, bucketed multisplit.
// K1: bucket histogram; persists per-block hist so K3 can skip its pass 1.
// ---------------------------------------------------------------------------
__global__ __launch_bounds__(256) void bucket_hist_kernel(
    const int* __restrict__ ei, int E0, int E, int* __restrict__ bhist,
    int* __restrict__ bhist_blk) {
    __shared__ int h[NB];
    int t = threadIdx.x;
    for (int i = t; i < NB; i += 256) h[i] = 0;
    __syncthreads();
    int base = blockIdx.x * BIN_CHUNK;
    int end = min(base + BIN_CHUNK, E);
    for (int e = base + t; e < end; e += 256) {
        int d = (e < E0) ? ei[E0 + e] : (e - E0);
        atomicAdd(&h[d >> 8], 1);
    }
    __syncthreads();
    for (int i = t; i < NB; i += 256) {
        int c = h[i];
        bhist_blk[blockIdx.x * NB + i] = c;
        if (c) atomicAdd(&bhist[i], c);
    }
}

// K2: scan 196 bucket counts -> bbase[NB+1], init bcursor, rowptr[N]=E
__global__ __launch_bounds__(256) void bucket_scan_kernel(
    const int* __restrict__ bhist, int* __restrict__ bbase,
    int* __restrict__ bcursor, int* __restrict__ rowptr, int E) {
    __shared__ int buf[256];
    int t = threadIdx.x;
    int v = (t < NB) ? bhist[t] : 0;
    int x = v;
    for (int off = 1; off < 256; off <<= 1) {
        buf[t] = x; __syncthreads();
        int y = (t >= off) ? buf[t - off] : 0;
        __syncthreads();
        x += y;
    }
    if (t < NB) {
        bbase[t] = x - v;      // exclusive
        bcursor[t] = x - v;
    }
    if (t == NB - 1) bbase[NB] = x;
    if (t == 0) rowptr[N_NODES] = E;
}

// K3: bin edges into bucket regions, packed src|(dst&255)<<16, burst writes.
// Local histogram comes pre-computed from K1 (bhist_blk) — no pass 1.
__global__ __launch_bounds__(256) void bin_kernel(
    const int* __restrict__ ei, int E0, int E,
    int* __restrict__ bcursor, unsigned int* __restrict__ ebuf,
    const int* __restrict__ bhist_blk) {
    __shared__ int h[NB];
    __shared__ int gbase[NB];
    int t = threadIdx.x;
    // reserve global bursts from persisted per-block hist
    for (int i = t; i < NB; i += 256) {
        int c = bhist_blk[blockIdx.x * NB + i];
        gbase[i] = c ? atomicAdd(&bcursor[i], c) : 0;
        h[i] = 0;  // local cursor
    }
    __syncthreads();
    int base = blockIdx.x * BIN_CHUNK;
    int end = min(base + BIN_CHUNK, E);
    for (int e = base + t; e < end; e += 256) {
        int s, d;
        if (e < E0) { s = ei[e]; d = ei[E0 + e]; }
        else        { s = e - E0; d = e - E0; }
        int b = d >> 8;
        int off = atomicAdd(&h[b], 1);
        ebuf[gbase[b] + off] = (unsigned)s | ((unsigned)(d & 255) << 16);
    }
}

// K4: one block per bucket: local deg-hist -> rowptr, LDS-staged CSR slice,
// fully-coalesced slice write.
__global__ __launch_bounds__(256) void build_kernel(
    const unsigned int* __restrict__ ebuf, const int* __restrict__ bbase,
    int* __restrict__ rowptr, int* __restrict__ csr_src) {
    __shared__ int h[256];
    __shared__ int lrp[257];
    __shared__ int stag[SLICE_MAX];
    int b = blockIdx.x, t = threadIdx.x;
    int e0 = bbase[b], e1 = bbase[b + 1];
    int cnt = e1 - e0;
    int n0 = b << 8;
    h[t] = 0;
    __syncthreads();
    // pass A: per-node degree histogram
    for (int i = t; i < cnt; i += 256)
        atomicAdd(&h[ebuf[e0 + i] >> 16], 1);
    __syncthreads();
    // scan 256 -> exclusive lrp
    int v = h[t], x = v;
    __shared__ int buf[256];
    for (int off = 1; off < 256; off <<= 1) {
        buf[t] = x; __syncthreads();
        int y = (t >= off) ? buf[t - off] : 0;
        __syncthreads();
        x += y;
    }
    lrp[t] = x - v;
    if (t == 255) lrp[256] = x;
    h[t] = 0;  // reuse as fill counters
    __syncthreads();
    int n = n0 + t;
    if (n < N_NODES) rowptr[n] = e0 + lrp[t];
    // pass B: place srcs into LDS slice
    for (int i = t; i < cnt; i += 256) {
        unsigned int v2 = ebuf[e0 + i];
        int dloc = v2 >> 16;
        int off = atomicAdd(&h[dloc], 1);
        stag[lrp[dloc] + off] = (int)(v2 & 0xFFFFu);
    }
    __syncthreads();
    // pass C: coalesced slice write-out
    for (int i = t; i < cnt; i += 256) csr_src[e0 + i] = stag[i];
}

// ---------------------------------------------------------------------------
// bf16 MFMA GEMM + fused attention-coefficient epilogue.
//   Cb[M,NREAL](bf16) = A[M,KK] x B[NREAL,KK]^T
//   a_src[n,h] = dot(Cb[n, h*D:(h+1)*D], att_src[h]); same for a_dst.
// C tile staged in LDS (reusing As/Bs space) -> coalesced C write + att dots
// from the exact bf16 values (numerics identical to the old att kernels).
// ---------------------------------------------------------------------------
template <int BM, int BN, int NREAL, int KK, int HEADS, typename InT>
__global__ __launch_bounds__(256) void gemm_att_kernel(
    const InT* __restrict__ A, const float* __restrict__ B,
    const float* __restrict__ att_src, const float* __restrict__ att_dst,
    unsigned short* __restrict__ Cb, float* __restrict__ a_src,
    float* __restrict__ a_dst, int M) {
    const int BK = 64, LDK = 72;
    const int NT = BN / 16;
    const int MT = BM / 64;            // m-tiles per wave
    const int LDC = NREAL + 8;
    __shared__ unsigned short smem[BM * LDK + BN * LDK];
    unsigned short* As = smem;
    unsigned short* Bs = smem + BM * LDK;
    const int t = threadIdx.x;
    const int wave = t >> 6, lane = t & 63;
    const int lrow = lane & 15, lkg = lane >> 4;
    const int bm = blockIdx.x * BM;

    floatx4 acc[MT][NT] = {};

    for (int k0 = 0; k0 < KK; k0 += BK) {
        __syncthreads();
        if constexpr (sizeof(InT) == 4) {
            for (int i = t; i < BM * 16; i += 256) {
                int r = i >> 4, c4 = (i & 15) << 2;
                int gr = bm + r;
                float4 v = make_float4(0.f, 0.f, 0.f, 0.f);
                if (gr < M) v = *(const float4*)&A[(size_t)gr * KK + k0 + c4];
                int o = r * LDK + c4;
                As[o] = f2b(v.x); As[o + 1] = f2b(v.y);
                As[o + 2] = f2b(v.z); As[o + 3] = f2b(v.w);
            }
        } else {
            for (int i = t; i < BM * 8; i += 256) {
                int r = i >> 3, c8 = (i & 7) << 3;
                int gr = bm + r;
                shortx8 v = {};
                if (gr < M) v = *(const shortx8*)&A[(size_t)gr * KK + k0 + c8];
                *(shortx8*)&As[r * LDK + c8] = v;
            }
        }
        for (int i = t; i < BN * 16; i += 256) {
            int r = i >> 4, c4 = (i & 15) << 2;
            float4 v = make_float4(0.f, 0.f, 0.f, 0.f);
            if (r < NREAL) v = *(const float4*)&B[(size_t)r * KK + k0 + c4];
            int o = r * LDK + c4;
            Bs[o] = f2b(v.x); Bs[o + 1] = f2b(v.y);
            Bs[o + 2] = f2b(v.z); Bs[o + 3] = f2b(v.w);
        }
        __syncthreads();

        for (int ks = 0; ks < BK; ks += 32) {
            int kc = ks + lkg * 8;
#pragma unroll
            for (int mt = 0; mt < MT; mt++) {
                int row = wave * (MT * 16) + mt * 16 + lrow;
                shortx8 a = *(const shortx8*)&As[row * LDK + kc];
#pragma unroll
                for (int nt = 0; nt < NT; nt++) {
                    shortx8 b = *(const shortx8*)&Bs[(nt * 16 + lrow) * LDK + kc];
                    acc[mt][nt] = __builtin_amdgcn_mfma_f32_16x16x32_bf16(a, b, acc[mt][nt], 0, 0, 0);
                }
            }
        }
    }

    // ---- epilogue: C tile -> LDS (bf16) ----
    __syncthreads();   // all MFMA reads of As/Bs done
    unsigned short* Cs = smem;     // BM*LDC <= BM*LDK + BN*LDK (checked)
#pragma unroll
    for (int mt = 0; mt < MT; mt++)
#pragma unroll
        for (int nt = 0; nt < NT; nt++)
#pragma unroll
            for (int r = 0; r < 4; r++) {
                int row = wave * (MT * 16) + mt * 16 + lkg * 4 + r;
                int col = nt * 16 + lrow;
                if (col < NREAL) Cs[row * LDC + col] = f2b(acc[mt][nt][r]);
            }
    __syncthreads();

    // coalesced C write-out (8-col chunks)
    const int NCH = NREAL / 8;
    for (int i = t; i < BM * NCH; i += 256) {
        int row = i / NCH, ch = i - row * NCH;
        if (bm + row < M)
            *(shortx8*)&Cb[(size_t)(bm + row) * NREAL + ch * 8] =
                *(const shortx8*)&Cs[row * LDC + ch * 8];
    }

    // fused att dots: 2 threads per row (which: 0=src, 1=dst)
    const int D = NREAL / HEADS;
    if (t < 2 * BM) {
        int row = t >> 1, which = t & 1;
        if (bm + row < M) {
            const float* av = which ? att_dst : att_src;
            float hs[HEADS];
#pragma unroll
            for (int h = 0; h < HEADS; h++) hs[h] = 0.f;
#pragma unroll
            for (int c = 0; c < NCH; c++) {
                float4 p = *(const float4*)&av[c * 8];
                float4 q = *(const float4*)&av[c * 8 + 4];
                shortx8 cv = *(const shortx8*)&Cs[row * LDC + c * 8];
                float s = b2f((unsigned short)cv[0]) * p.x
                        + b2f((unsigned short)cv[1]) * p.y
                        + b2f((unsigned short)cv[2]) * p.z
                        + b2f((unsigned short)cv[3]) * p.w
                        + b2f((unsigned short)cv[4]) * q.x
                        + b2f((unsigned short)cv[5]) * q.y
                        + b2f((unsigned short)cv[6]) * q.z
                        + b2f((unsigned short)cv[7]) * q.w;
                hs[(c * 8) / D] += s;
            }
            float* outp = which ? a_dst : a_src;
#pragma unroll
            for (int h = 0; h < HEADS; h++)
                outp[(size_t)(bm + row) * HEADS + h] = hs[h];
        }
    }
}

// ---------------------------------------------------------------------------
// Aggregation layer 1: one WAVE per node. dwordx4 gather (4 edges per
// wave-instruction) + 2-stage software pipeline across 16-edge chunks.
// ---------------------------------------------------------------------------
__global__ __launch_bounds__(256) void agg1_kernel(
    const unsigned short* __restrict__ h1b, const float* __restrict__ a_src,
    const float* __restrict__ a_dst, const int* __restrict__ rowptr,
    const int* __restrict__ csr_src, const float* __restrict__ b1,
    unsigned short* __restrict__ zb, int N) {
    int wave = threadIdx.x >> 6, lane = threadIdx.x & 63;
    int n = blockIdx.x * 4 + wave;
    if (n >= N) return;
    int eg = lane >> 4;        // edge-slot group 0..3
    int fpos = lane & 15;      // feature block: feats fpos*8 .. fpos*8+7
    int hd = fpos >> 2;        // head of this feature block
    int lidx = lane >> 2;      // edge slot 0..15 in coeff phase
    int lh = lane & 3;         // head in coeff phase
    float adn = a_dst[n * 4 + lh];
    int beg = rowptr[n], deg = rowptr[n + 1] - beg;

    float acc[8] = {0.f, 0.f, 0.f, 0.f, 0.f, 0.f, 0.f, 0.f};
    float den = 0.f;

    // prologue: coeff inputs for chunk 0
    int s_e = (lidx < deg) ? csr_src[beg + lidx] : 0;
    float asv = a_src[(s_e << 2) + lh];

    for (int c0 = 0; c0 < deg; c0 += 16) {
        float l = asv + adn;
        l = l > 0.f ? l : NEG_SLOPE * l;
        float w_e = (c0 + lidx < deg) ? __expf(l) : 0.f;  // zero-pad dead edges
        int cnt = min(16, deg - c0);
        int s4[4]; float w4[4]; shortx8 v4[4];
#pragma unroll
        for (int q = 0; q < 4; q++) {
            int el = (q << 2) + eg;
            s4[q] = __shfl(s_e, el << 2);
            w4[q] = __shfl(w_e, (el << 2) + hd);
        }
#pragma unroll
        for (int q = 0; q < 4; q++) {
            if (q * 4 < cnt)
                v4[q] = *(const shortx8*)&h1b[(size_t)s4[q] * 128 + fpos * 8];
        }
        // prefetch next chunk's coeff inputs (overlaps gather latency)
        int nidx = c0 + 16 + lidx;
        int s_n = (nidx < deg) ? csr_src[beg + nidx] : 0;
        float asn = a_src[(s_n << 2) + lh];
#pragma unroll
        for (int q = 0; q < 4; q++) {
            if (q * 4 < cnt) {
                float w = w4[q];
                den += w;
#pragma unroll
                for (int j = 0; j < 8; j++)
                    acc[j] += w * b2f((unsigned short)v4[q][j]);
            }
        }
        s_e = s_n; asv = asn;
    }
#pragma unroll
    for (int j = 0; j < 8; j++) {
        acc[j] += __shfl_xor(acc[j], 16);
        acc[j] += __shfl_xor(acc[j], 32);
    }
    den += __shfl_xor(den, 16);
    den += __shfl_xor(den, 32);
    if (lane < 16) {
        float inv = 1.f / den;
        float4 bb0 = *(const float4*)&b1[fpos * 8];
        float4 bb1 = *(const float4*)&b1[fpos * 8 + 4];
        shortx8 r;
        r[0] = (short)f2b(fmaxf(acc[0] * inv + bb0.x, 0.f));
        r[1] = (short)f2b(fmaxf(acc[1] * inv + bb0.y, 0.f));
        r[2] = (short)f2b(fmaxf(acc[2] * inv + bb0.z, 0.f));
        r[3] = (short)f2b(fmaxf(acc[3] * inv + bb0.w, 0.f));
        r[4] = (short)f2b(fmaxf(acc[4] * inv + bb1.x, 0.f));
        r[5] = (short)f2b(fmaxf(acc[5] * inv + bb1.y, 0.f));
        r[6] = (short)f2b(fmaxf(acc[6] * inv + bb1.z, 0.f));
        r[7] = (short)f2b(fmaxf(acc[7] * inv + bb1.w, 0.f));
        *(shortx8*)&zb[(size_t)n * 128 + fpos * 8] = r;
    }
}

// ---------------------------------------------------------------------------
// Aggregation layer 2: one wave per node, H=1, D=40 (80B rows). 3 edges per
// wave-instruction (20 lanes x ushort2), coeff phase covers 48 edges.
// ---------------------------------------------------------------------------
__global__ __launch_bounds__(256) void agg2_kernel(
    const unsigned short* __restrict__ h2b, const float* __restrict__ a_src,
    const float* __restrict__ a_dst, const int* __restrict__ rowptr,
    const int* __restrict__ csr_src, const float* __restrict__ b2,
    float* __restrict__ out, int N) {
    int wave = threadIdx.x >> 6, lane = threadIdx.x & 63;
    int n = blockIdx.x * 4 + wave;
    if (n >= N) return;
    int eg = (lane >= 40) ? 2 : (lane >= 20 ? 1 : 0);  // edge-slot 0..2
    int fp = lane - eg * 20;                            // 0..19 (lanes 60-63: 20-23)
    bool act = fp < 20;
    float adn = a_dst[n];
    int beg = rowptr[n], deg = rowptr[n + 1] - beg;

    float2 acc = {0.f, 0.f};
    float den = 0.f;
    for (int c0 = 0; c0 < deg; c0 += 48) {
        int idx = c0 + lane;
        bool cv = (lane < 48) && (idx < deg);
        int s_e = cv ? csr_src[beg + idx] : 0;
        float l = a_src[s_e] + adn;
        l = l > 0.f ? l : NEG_SLOPE * l;
        float w_e = cv ? __expf(l) : 0.f;   // zero-pad dead edges
        int cnt = min(48, deg - c0);
#pragma unroll
        for (int qq = 0; qq < 4; qq++) {
            if (qq * 12 < cnt) {
                int s4[4]; float w4[4]; ushort2 v4[4];
#pragma unroll
                for (int q = 0; q < 4; q++) {
                    int el = qq * 12 + q * 3 + eg;
                    s4[q] = __shfl(s_e, el);
                    w4[q] = __shfl(w_e, el);
                }
#pragma unroll
                for (int q = 0; q < 4; q++) {
                    if (act)
                        v4[q] = *(const ushort2*)&h2b[(size_t)s4[q] * 40 + fp * 2];
                }
#pragma unroll
                for (int q = 0; q < 4; q++) {
                    float w = w4[q];
                    den += w;
                    if (act) {
                        acc.x += w * b2f(v4[q].x);
                        acc.y += w * b2f(v4[q].y);
                    }
                }
            }
        }
    }
    // combine 3 edge-slot partials: lanes {fp, fp+20, fp+40}
    float a1x = __shfl(acc.x, fp + 20), a2x = __shfl(acc.x, fp + 40);
    float a1y = __shfl(acc.y, fp + 20), a2y = __shfl(acc.y, fp + 40);
    float d1  = __shfl(den,  fp + 20), d2  = __shfl(den,  fp + 40);
    if (lane < 20) {
        float sx = acc.x + a1x + a2x;
        float sy = acc.y + a1y + a2y;
        float dtot = den + d1 + d2;
        float inv = 1.f / dtot;
        float2 bb = *(const float2*)&b2[fp * 2];
        float2 o;
        o.x = sx * inv + bb.x;
        o.y = sy * inv + bb.y;
        *(float2*)&out[(size_t)n * 40 + fp * 2] = o;
    }
}

// ---------------------------------------------------------------------------
extern "C" void kernel_launch(void* const* d_in, const int* in_sizes, int n_in,
                              void* d_out, int out_size, void* d_ws, size_t ws_size,
                              hipStream_t stream) {
    const float* x        = (const float*)d_in[0];
    const int*   ei       = (const int*)d_in[1];
    const float* W1       = (const float*)d_in[2];
    const float* att_src1 = (const float*)d_in[3];
    const float* att_dst1 = (const float*)d_in[4];
    const float* b1       = (const float*)d_in[5];
    const float* W2       = (const float*)d_in[6];
    const float* att_src2 = (const float*)d_in[7];
    const float* att_dst2 = (const float*)d_in[8];
    const float* b2       = (const float*)d_in[9];
    float* out = (float*)d_out;

    const int N  = N_NODES;
    const int E0 = in_sizes[1] / 2;
    const int E  = E0 + N;
    const int NBLK = (E + BIN_CHUNK - 1) / BIN_CHUNK;

    char* ws = (char*)d_ws;
    unsigned short* h1b = (unsigned short*)(ws + 0);          // 12,800,000
    unsigned short* zb  = (unsigned short*)(ws + 12800000);   // 12,800,000
    unsigned short* h2b = (unsigned short*)(ws + 25600000);   //  4,000,000
    float* a_src1 = (float*)(ws + 29600000);                  //    800,000
    float* a_dst1 = (float*)(ws + 30400000);                  //    800,000
    float* a_src2 = (float*)(ws + 31200000);                  //    200,000
    float* a_dst2 = (float*)(ws + 31400000);                  //    200,000
    int*   rowptr = (int*)(ws + 31600000);                    //    200,004
    int*   bhist  = (int*)(ws + 31800192);                    //        784
    int*   bbase  = (int*)(ws + 31801088);                    //        788
    int*   bcursor= (int*)(ws + 31801984);                    //        784
    unsigned int* ebuf = (unsigned int*)(ws + 31802880);      //  3,400,000
    int*   csr_src= (int*)(ws + 35202880);                    //  3,400,000
    int*   bhist_blk = (int*)(ws + 38602880);                 //    ~81,536
    // total ~38.7 MB

    hipMemsetAsync(bhist, 0, NB * sizeof(int), stream);

    bucket_hist_kernel<<<NBLK, 256, 0, stream>>>(ei, E0, E, bhist, bhist_blk);
    bucket_scan_kernel<<<1, 256, 0, stream>>>(bhist, bbase, bcursor, rowptr, E);
    bin_kernel<<<NBLK, 256, 0, stream>>>(ei, E0, E, bcursor, ebuf, bhist_blk);
    build_kernel<<<NB, 256, 0, stream>>>(ebuf, bbase, rowptr, csr_src);

    // layer 1: h1b = bf16(x @ W1^T), fused a_src1/a_dst1
    gemm_att_kernel<128, 128, 128, 256, 4, float>
        <<<(N + 127) / 128, 256, 0, stream>>>(x, W1, att_src1, att_dst1,
                                              h1b, a_src1, a_dst1, N);
    agg1_kernel<<<(N + 3) / 4, 256, 0, stream>>>(h1b, a_src1, a_dst1, rowptr, csr_src, b1, zb, N);

    // layer 2: h2b = bf16(zb @ W2^T), fused a_src2/a_dst2
    gemm_att_kernel<64, 48, 40, 128, 1, unsigned short>
        <<<(N + 63) / 64, 256, 0, stream>>>(zb, W2, att_src2, att_dst2,
                                            h2b, a_src2, a_dst2, N);
    agg2_kernel<<<(N + 3) / 4, 256, 0, stream>>>(h2b, a_src2, a_dst2, rowptr, csr_src, b2, out, N);
}

// Round 6
// 221.432 us; speedup vs baseline: 1.2345x; 1.0697x over previous
//
#include <hip/hip_runtime.h>
#include <hip/hip_bf16.h>
#include <cstdint>
#include <cstddef>

#define N_NODES 50000
#define NEG_SLOPE 0.2f
#define NB 196            // buckets of 256 nodes: (50000+255)/256
#define BIN_CHUNK 8192    // edges per block in hist/bin kernels
#define SLICE_MAX 14336   // LDS slice capacity (mean ~4345, 3.3x headroom)

typedef float floatx4 __attribute__((ext_vector_type(4)));
typedef short shortx8 __attribute__((ext_vector_type(8)));

// ---- fp32 <-> bf16 helpers (RNE) --------------------------------------------
__device__ __forceinline__ unsigned short f2b(float f) {
    union { float f; unsigned u; } v; v.f = f;
    unsigned u = v.u;
    return (unsigned short)((u + 0x7FFFu + ((u >> 16) & 1u)) >> 16);
}
__device__ __forceinline__ float b2f(unsigned short b) {
    union { unsigned u; float f; } v; v.u = ((unsigned)b) << 16;
    return v.f;
}

// ---------------------------------------------------------------------------
// CSR build, bucketed multisplit.
// K1: bucket histogram; persists per-block hist so K3 can skip its pass 1.
// ---------------------------------------------------------------------------
__global__ __launch_bounds__(256) void bucket_hist_kernel(
    const int* __restrict__ ei, int E0, int E, int* __restrict__ bhist,
    int* __restrict__ bhist_blk) {
    __shared__ int h[NB];
    int t = threadIdx.x;
    for (int i = t; i < NB; i += 256) h[i] = 0;
    __syncthreads();
    int base = blockIdx.x * BIN_CHUNK;
    int end = min(base + BIN_CHUNK, E);
    for (int e = base + t; e < end; e += 256) {
        int d = (e < E0) ? ei[E0 + e] : (e - E0);
        atomicAdd(&h[d >> 8], 1);
    }
    __syncthreads();
    for (int i = t; i < NB; i += 256) {
        int c = h[i];
        bhist_blk[blockIdx.x * NB + i] = c;
        if (c) atomicAdd(&bhist[i], c);
    }
}

// K2: scan 196 bucket counts -> bbase[NB+1], init bcursor, rowptr[N]=E
__global__ __launch_bounds__(256) void bucket_scan_kernel(
    const int* __restrict__ bhist, int* __restrict__ bbase,
    int* __restrict__ bcursor, int* __restrict__ rowptr, int E) {
    __shared__ int buf[256];
    int t = threadIdx.x;
    int v = (t < NB) ? bhist[t] : 0;
    int x = v;
    for (int off = 1; off < 256; off <<= 1) {
        buf[t] = x; __syncthreads();
        int y = (t >= off) ? buf[t - off] : 0;
        __syncthreads();
        x += y;
    }
    if (t < NB) {
        bbase[t] = x - v;      // exclusive
        bcursor[t] = x - v;
    }
    if (t == NB - 1) bbase[NB] = x;
    if (t == 0) rowptr[N_NODES] = E;
}

// K3: bin edges into bucket regions, packed src|(dst&255)<<16, burst writes.
// Local histogram comes pre-computed from K1 (bhist_blk) — no pass 1.
__global__ __launch_bounds__(256) void bin_kernel(
    const int* __restrict__ ei, int E0, int E,
    int* __restrict__ bcursor, unsigned int* __restrict__ ebuf,
    const int* __restrict__ bhist_blk) {
    __shared__ int h[NB];
    __shared__ int gbase[NB];
    int t = threadIdx.x;
    // reserve global bursts from persisted per-block hist
    for (int i = t; i < NB; i += 256) {
        int c = bhist_blk[blockIdx.x * NB + i];
        gbase[i] = c ? atomicAdd(&bcursor[i], c) : 0;
        h[i] = 0;  // local cursor
    }
    __syncthreads();
    int base = blockIdx.x * BIN_CHUNK;
    int end = min(base + BIN_CHUNK, E);
    for (int e = base + t; e < end; e += 256) {
        int s, d;
        if (e < E0) { s = ei[e]; d = ei[E0 + e]; }
        else        { s = e - E0; d = e - E0; }
        int b = d >> 8;
        int off = atomicAdd(&h[b], 1);
        ebuf[gbase[b] + off] = (unsigned)s | ((unsigned)(d & 255) << 16);
    }
}

// K4: one block per bucket: local deg-hist -> rowptr, LDS-staged CSR slice,
// fully-coalesced slice write.
__global__ __launch_bounds__(256) void build_kernel(
    const unsigned int* __restrict__ ebuf, const int* __restrict__ bbase,
    int* __restrict__ rowptr, int* __restrict__ csr_src) {
    __shared__ int h[256];
    __shared__ int lrp[257];
    __shared__ int stag[SLICE_MAX];
    int b = blockIdx.x, t = threadIdx.x;
    int e0 = bbase[b], e1 = bbase[b + 1];
    int cnt = e1 - e0;
    int n0 = b << 8;
    h[t] = 0;
    __syncthreads();
    // pass A: per-node degree histogram
    for (int i = t; i < cnt; i += 256)
        atomicAdd(&h[ebuf[e0 + i] >> 16], 1);
    __syncthreads();
    // scan 256 -> exclusive lrp
    int v = h[t], x = v;
    __shared__ int buf[256];
    for (int off = 1; off < 256; off <<= 1) {
        buf[t] = x; __syncthreads();
        int y = (t >= off) ? buf[t - off] : 0;
        __syncthreads();
        x += y;
    }
    lrp[t] = x - v;
    if (t == 255) lrp[256] = x;
    h[t] = 0;  // reuse as fill counters
    __syncthreads();
    int n = n0 + t;
    if (n < N_NODES) rowptr[n] = e0 + lrp[t];
    // pass B: place srcs into LDS slice
    for (int i = t; i < cnt; i += 256) {
        unsigned int v2 = ebuf[e0 + i];
        int dloc = v2 >> 16;
        int off = atomicAdd(&h[dloc], 1);
        stag[lrp[dloc] + off] = (int)(v2 & 0xFFFFu);
    }
    __syncthreads();
    // pass C: coalesced slice write-out
    for (int i = t; i < cnt; i += 256) csr_src[e0 + i] = stag[i];
}

// ---------------------------------------------------------------------------
// bf16 MFMA GEMM + fused attention-coefficient epilogue.
// v2: register-batched staging (all tile loads issue back-to-back -> deep
// MLP, no per-load vmcnt serialization) + 1-deep cross-K prefetch (next
// tile's loads overlap current tile's MFMAs). Values/order bit-identical.
// ---------------------------------------------------------------------------
template <int BM, int BN, int NREAL, int KK, int HEADS, typename InT>
__global__ __launch_bounds__(256) void gemm_att_kernel(
    const InT* __restrict__ A, const float* __restrict__ B,
    const float* __restrict__ att_src, const float* __restrict__ att_dst,
    unsigned short* __restrict__ Cb, float* __restrict__ a_src,
    float* __restrict__ a_dst, int M) {
    const int BK = 64, LDK = 72;
    const int NT = BN / 16;
    const int MT = BM / 64;            // m-tiles per wave
    const int NKI = KK / BK;
    const int LDC = NREAL + 8;
    const int NAf = BM * 16 / 256;     // float4 A-loads per thread (fp32 in)
    const int NAs = BM * 8 / 256;      // shortx8 A-loads per thread (bf16 in)
    const int NBv = BN * 16 / 256;     // float4 B-loads per thread
    constexpr int SMEM = ((BM + BN) * LDK > BM * LDC) ? (BM + BN) * LDK : BM * LDC;
    __shared__ unsigned short smem[SMEM];
    unsigned short* As = smem;
    unsigned short* Bs = smem + BM * LDK;
    const int t = threadIdx.x;
    const int wave = t >> 6, lane = t & 63;
    const int lrow = lane & 15, lkg = lane >> 4;
    const int bm = blockIdx.x * BM;

    floatx4 acc[MT][NT] = {};

    float4 avf[(sizeof(InT) == 4) ? NAf : 1];
    shortx8 avs[(sizeof(InT) == 2) ? NAs : 1];
    float4 bv[NBv];

    // ---- load first K-tile into regs (all loads issue back-to-back) ----
    {
        const int k0 = 0;
        if constexpr (sizeof(InT) == 4) {
#pragma unroll
            for (int q = 0; q < NAf; q++) {
                int i = t + q * 256;
                int r = i >> 4, c4 = (i & 15) << 2;
                int gr = bm + r;
                avf[q] = (gr < M) ? *(const float4*)&A[(size_t)gr * KK + k0 + c4]
                                  : make_float4(0.f, 0.f, 0.f, 0.f);
            }
        } else {
#pragma unroll
            for (int q = 0; q < NAs; q++) {
                int i = t + q * 256;
                int r = i >> 3, c8 = (i & 7) << 3;
                int gr = bm + r;
                shortx8 z = {};
                avs[q] = (gr < M) ? *(const shortx8*)&A[(size_t)gr * KK + k0 + c8] : z;
            }
        }
#pragma unroll
        for (int q = 0; q < NBv; q++) {
            int i = t + q * 256;
            int r = i >> 4, c4 = (i & 15) << 2;
            bv[q] = (r < NREAL) ? *(const float4*)&B[(size_t)r * KK + k0 + c4]
                                : make_float4(0.f, 0.f, 0.f, 0.f);
        }
    }

    for (int ki = 0; ki < NKI; ki++) {
        __syncthreads();   // previous MFMA phase done reading LDS
        // ---- regs -> LDS (convert fp32->bf16 here; same values as before) --
        if constexpr (sizeof(InT) == 4) {
#pragma unroll
            for (int q = 0; q < NAf; q++) {
                int i = t + q * 256;
                int r = i >> 4, c4 = (i & 15) << 2;
                int o = r * LDK + c4;
                float4 v = avf[q];
                As[o] = f2b(v.x); As[o + 1] = f2b(v.y);
                As[o + 2] = f2b(v.z); As[o + 3] = f2b(v.w);
            }
        } else {
#pragma unroll
            for (int q = 0; q < NAs; q++) {
                int i = t + q * 256;
                int r = i >> 3, c8 = (i & 7) << 3;
                *(shortx8*)&As[r * LDK + c8] = avs[q];
            }
        }
#pragma unroll
        for (int q = 0; q < NBv; q++) {
            int i = t + q * 256;
            int r = i >> 4, c4 = (i & 15) << 2;
            int o = r * LDK + c4;
            float4 v = bv[q];
            Bs[o] = f2b(v.x); Bs[o + 1] = f2b(v.y);
            Bs[o + 2] = f2b(v.z); Bs[o + 3] = f2b(v.w);
        }
        // ---- prefetch next K-tile (overlaps MFMA below) ----
        if (ki + 1 < NKI) {
            const int k0 = (ki + 1) * BK;
            if constexpr (sizeof(InT) == 4) {
#pragma unroll
                for (int q = 0; q < NAf; q++) {
                    int i = t + q * 256;
                    int r = i >> 4, c4 = (i & 15) << 2;
                    int gr = bm + r;
                    avf[q] = (gr < M) ? *(const float4*)&A[(size_t)gr * KK + k0 + c4]
                                      : make_float4(0.f, 0.f, 0.f, 0.f);
                }
            } else {
#pragma unroll
                for (int q = 0; q < NAs; q++) {
                    int i = t + q * 256;
                    int r = i >> 3, c8 = (i & 7) << 3;
                    int gr = bm + r;
                    shortx8 z = {};
                    avs[q] = (gr < M) ? *(const shortx8*)&A[(size_t)gr * KK + k0 + c8] : z;
                }
            }
#pragma unroll
            for (int q = 0; q < NBv; q++) {
                int i = t + q * 256;
                int r = i >> 4, c4 = (i & 15) << 2;
                bv[q] = (r < NREAL) ? *(const float4*)&B[(size_t)r * KK + k0 + c4]
                                    : make_float4(0.f, 0.f, 0.f, 0.f);
            }
        }
        __syncthreads();
        // ---- MFMA phase (order identical to previous versions) ----
        for (int ks = 0; ks < BK; ks += 32) {
            int kc = ks + lkg * 8;
#pragma unroll
            for (int mt = 0; mt < MT; mt++) {
                int row = wave * (MT * 16) + mt * 16 + lrow;
                shortx8 a = *(const shortx8*)&As[row * LDK + kc];
#pragma unroll
                for (int nt = 0; nt < NT; nt++) {
                    shortx8 b = *(const shortx8*)&Bs[(nt * 16 + lrow) * LDK + kc];
                    acc[mt][nt] = __builtin_amdgcn_mfma_f32_16x16x32_bf16(a, b, acc[mt][nt], 0, 0, 0);
                }
            }
        }
    }

    // ---- epilogue: C tile -> LDS (bf16) ----
    __syncthreads();   // all MFMA reads of As/Bs done
    unsigned short* Cs = smem;
#pragma unroll
    for (int mt = 0; mt < MT; mt++)
#pragma unroll
        for (int nt = 0; nt < NT; nt++)
#pragma unroll
            for (int r = 0; r < 4; r++) {
                int row = wave * (MT * 16) + mt * 16 + lkg * 4 + r;
                int col = nt * 16 + lrow;
                if (col < NREAL) Cs[row * LDC + col] = f2b(acc[mt][nt][r]);
            }
    __syncthreads();

    // coalesced C write-out (8-col chunks)
    const int NCH = NREAL / 8;
    for (int i = t; i < BM * NCH; i += 256) {
        int row = i / NCH, ch = i - row * NCH;
        if (bm + row < M)
            *(shortx8*)&Cb[(size_t)(bm + row) * NREAL + ch * 8] =
                *(const shortx8*)&Cs[row * LDC + ch * 8];
    }

    // fused att dots: 2 threads per row (which: 0=src, 1=dst)
    const int D = NREAL / HEADS;
    if (t < 2 * BM) {
        int row = t >> 1, which = t & 1;
        if (bm + row < M) {
            const float* av = which ? att_dst : att_src;
            float hs[HEADS];
#pragma unroll
            for (int h = 0; h < HEADS; h++) hs[h] = 0.f;
#pragma unroll
            for (int c = 0; c < NCH; c++) {
                float4 p = *(const float4*)&av[c * 8];
                float4 q = *(const float4*)&av[c * 8 + 4];
                shortx8 cv = *(const shortx8*)&Cs[row * LDC + c * 8];
                float s = b2f((unsigned short)cv[0]) * p.x
                        + b2f((unsigned short)cv[1]) * p.y
                        + b2f((unsigned short)cv[2]) * p.z
                        + b2f((unsigned short)cv[3]) * p.w
                        + b2f((unsigned short)cv[4]) * q.x
                        + b2f((unsigned short)cv[5]) * q.y
                        + b2f((unsigned short)cv[6]) * q.z
                        + b2f((unsigned short)cv[7]) * q.w;
                hs[(c * 8) / D] += s;
            }
            float* outp = which ? a_dst : a_src;
#pragma unroll
            for (int h = 0; h < HEADS; h++)
                outp[(size_t)(bm + row) * HEADS + h] = hs[h];
        }
    }
}

// ---------------------------------------------------------------------------
// Aggregation layer 1: one WAVE per node. dwordx4 gather (4 edges per
// wave-instruction) + 2-stage software pipeline across 16-edge chunks.
// ---------------------------------------------------------------------------
__global__ __launch_bounds__(256) void agg1_kernel(
    const unsigned short* __restrict__ h1b, const float* __restrict__ a_src,
    const float* __restrict__ a_dst, const int* __restrict__ rowptr,
    const int* __restrict__ csr_src, const float* __restrict__ b1,
    unsigned short* __restrict__ zb, int N) {
    int wave = threadIdx.x >> 6, lane = threadIdx.x & 63;
    int n = blockIdx.x * 4 + wave;
    if (n >= N) return;
    int eg = lane >> 4;        // edge-slot group 0..3
    int fpos = lane & 15;      // feature block: feats fpos*8 .. fpos*8+7
    int hd = fpos >> 2;        // head of this feature block
    int lidx = lane >> 2;      // edge slot 0..15 in coeff phase
    int lh = lane & 3;         // head in coeff phase
    float adn = a_dst[n * 4 + lh];
    int beg = rowptr[n], deg = rowptr[n + 1] - beg;

    float acc[8] = {0.f, 0.f, 0.f, 0.f, 0.f, 0.f, 0.f, 0.f};
    float den = 0.f;

    // prologue: coeff inputs for chunk 0
    int s_e = (lidx < deg) ? csr_src[beg + lidx] : 0;
    float asv = a_src[(s_e << 2) + lh];

    for (int c0 = 0; c0 < deg; c0 += 16) {
        float l = asv + adn;
        l = l > 0.f ? l : NEG_SLOPE * l;
        float w_e = (c0 + lidx < deg) ? __expf(l) : 0.f;  // zero-pad dead edges
        int cnt = min(16, deg - c0);
        int s4[4]; float w4[4]; shortx8 v4[4];
#pragma unroll
        for (int q = 0; q < 4; q++) {
            int el = (q << 2) + eg;
            s4[q] = __shfl(s_e, el << 2);
            w4[q] = __shfl(w_e, (el << 2) + hd);
        }
#pragma unroll
        for (int q = 0; q < 4; q++) {
            if (q * 4 < cnt)
                v4[q] = *(const shortx8*)&h1b[(size_t)s4[q] * 128 + fpos * 8];
        }
        // prefetch next chunk's coeff inputs (overlaps gather latency)
        int nidx = c0 + 16 + lidx;
        int s_n = (nidx < deg) ? csr_src[beg + nidx] : 0;
        float asn = a_src[(s_n << 2) + lh];
#pragma unroll
        for (int q = 0; q < 4; q++) {
            if (q * 4 < cnt) {
                float w = w4[q];
                den += w;
#pragma unroll
                for (int j = 0; j < 8; j++)
                    acc[j] += w * b2f((unsigned short)v4[q][j]);
            }
        }
        s_e = s_n; asv = asn;
    }
#pragma unroll
    for (int j = 0; j < 8; j++) {
        acc[j] += __shfl_xor(acc[j], 16);
        acc[j] += __shfl_xor(acc[j], 32);
    }
    den += __shfl_xor(den, 16);
    den += __shfl_xor(den, 32);
    if (lane < 16) {
        float inv = 1.f / den;
        float4 bb0 = *(const float4*)&b1[fpos * 8];
        float4 bb1 = *(const float4*)&b1[fpos * 8 + 4];
        shortx8 r;
        r[0] = (short)f2b(fmaxf(acc[0] * inv + bb0.x, 0.f));
        r[1] = (short)f2b(fmaxf(acc[1] * inv + bb0.y, 0.f));
        r[2] = (short)f2b(fmaxf(acc[2] * inv + bb0.z, 0.f));
        r[3] = (short)f2b(fmaxf(acc[3] * inv + bb0.w, 0.f));
        r[4] = (short)f2b(fmaxf(acc[4] * inv + bb1.x, 0.f));
        r[5] = (short)f2b(fmaxf(acc[5] * inv + bb1.y, 0.f));
        r[6] = (short)f2b(fmaxf(acc[6] * inv + bb1.z, 0.f));
        r[7] = (short)f2b(fmaxf(acc[7] * inv + bb1.w, 0.f));
        *(shortx8*)&zb[(size_t)n * 128 + fpos * 8] = r;
    }
}

// ---------------------------------------------------------------------------
// Aggregation layer 2: one wave per node, H=1, D=40 (80B rows). 3 edges per
// wave-instruction (20 lanes x ushort2), coeff phase covers 48 edges.
// ---------------------------------------------------------------------------
__global__ __launch_bounds__(256) void agg2_kernel(
    const unsigned short* __restrict__ h2b, const float* __restrict__ a_src,
    const float* __restrict__ a_dst, const int* __restrict__ rowptr,
    const int* __restrict__ csr_src, const float* __restrict__ b2,
    float* __restrict__ out, int N) {
    int wave = threadIdx.x >> 6, lane = threadIdx.x & 63;
    int n = blockIdx.x * 4 + wave;
    if (n >= N) return;
    int eg = (lane >= 40) ? 2 : (lane >= 20 ? 1 : 0);  // edge-slot 0..2
    int fp = lane - eg * 20;                            // 0..19 (lanes 60-63: 20-23)
    bool act = fp < 20;
    float adn = a_dst[n];
    int beg = rowptr[n], deg = rowptr[n + 1] - beg;

    float2 acc = {0.f, 0.f};
    float den = 0.f;
    for (int c0 = 0; c0 < deg; c0 += 48) {
        int idx = c0 + lane;
        bool cv = (lane < 48) && (idx < deg);
        int s_e = cv ? csr_src[beg + idx] : 0;
        float l = a_src[s_e] + adn;
        l = l > 0.f ? l : NEG_SLOPE * l;
        float w_e = cv ? __expf(l) : 0.f;   // zero-pad dead edges
        int cnt = min(48, deg - c0);
#pragma unroll
        for (int qq = 0; qq < 4; qq++) {
            if (qq * 12 < cnt) {
                int s4[4]; float w4[4]; ushort2 v4[4];
#pragma unroll
                for (int q = 0; q < 4; q++) {
                    int el = qq * 12 + q * 3 + eg;
                    s4[q] = __shfl(s_e, el);
                    w4[q] = __shfl(w_e, el);
                }
#pragma unroll
                for (int q = 0; q < 4; q++) {
                    if (act)
                        v4[q] = *(const ushort2*)&h2b[(size_t)s4[q] * 40 + fp * 2];
                }
#pragma unroll
                for (int q = 0; q < 4; q++) {
                    float w = w4[q];
                    den += w;
                    if (act) {
                        acc.x += w * b2f(v4[q].x);
                        acc.y += w * b2f(v4[q].y);
                    }
                }
            }
        }
    }
    // combine 3 edge-slot partials: lanes {fp, fp+20, fp+40}
    float a1x = __shfl(acc.x, fp + 20), a2x = __shfl(acc.x, fp + 40);
    float a1y = __shfl(acc.y, fp + 20), a2y = __shfl(acc.y, fp + 40);
    float d1  = __shfl(den,  fp + 20), d2  = __shfl(den,  fp + 40);
    if (lane < 20) {
        float sx = acc.x + a1x + a2x;
        float sy = acc.y + a1y + a2y;
        float dtot = den + d1 + d2;
        float inv = 1.f / dtot;
        float2 bb = *(const float2*)&b2[fp * 2];
        float2 o;
        o.x = sx * inv + bb.x;
        o.y = sy * inv + bb.y;
        *(float2*)&out[(size_t)n * 40 + fp * 2] = o;
    }
}

// ---------------------------------------------------------------------------
extern "C" void kernel_launch(void* const* d_in, const int* in_sizes, int n_in,
                              void* d_out, int out_size, void* d_ws, size_t ws_size,
                              hipStream_t stream) {
    const float* x        = (const float*)d_in[0];
    const int*   ei       = (const int*)d_in[1];
    const float* W1       = (const float*)d_in[2];
    const float* att_src1 = (const float*)d_in[3];
    const float* att_dst1 = (const float*)d_in[4];
    const float* b1       = (const float*)d_in[5];
    const float* W2       = (const float*)d_in[6];
    const float* att_src2 = (const float*)d_in[7];
    const float* att_dst2 = (const float*)d_in[8];
    const float* b2       = (const float*)d_in[9];
    float* out = (float*)d_out;

    const int N  = N_NODES;
    const int E0 = in_sizes[1] / 2;
    const int E  = E0 + N;
    const int NBLK = (E + BIN_CHUNK - 1) / BIN_CHUNK;

    char* ws = (char*)d_ws;
    unsigned short* h1b = (unsigned short*)(ws + 0);          // 12,800,000
    unsigned short* zb  = (unsigned short*)(ws + 12800000);   // 12,800,000
    unsigned short* h2b = (unsigned short*)(ws + 25600000);   //  4,000,000
    float* a_src1 = (float*)(ws + 29600000);                  //    800,000
    float* a_dst1 = (float*)(ws + 30400000);                  //    800,000
    float* a_src2 = (float*)(ws + 31200000);                  //    200,000
    float* a_dst2 = (float*)(ws + 31400000);                  //    200,000
    int*   rowptr = (int*)(ws + 31600000);                    //    200,004
    int*   bhist  = (int*)(ws + 31800192);                    //        784
    int*   bbase  = (int*)(ws + 31801088);                    //        788
    int*   bcursor= (int*)(ws + 31801984);                    //        784
    unsigned int* ebuf = (unsigned int*)(ws + 31802880);      //  3,400,000
    int*   csr_src= (int*)(ws + 35202880);                    //  3,400,000
    int*   bhist_blk = (int*)(ws + 38602880);                 //    ~81,536
    // total ~38.7 MB

    hipMemsetAsync(bhist, 0, NB * sizeof(int), stream);

    bucket_hist_kernel<<<NBLK, 256, 0, stream>>>(ei, E0, E, bhist, bhist_blk);
    bucket_scan_kernel<<<1, 256, 0, stream>>>(bhist, bbase, bcursor, rowptr, E);
    bin_kernel<<<NBLK, 256, 0, stream>>>(ei, E0, E, bcursor, ebuf, bhist_blk);
    build_kernel<<<NB, 256, 0, stream>>>(ebuf, bbase, rowptr, csr_src);

    // layer 1: h1b = bf16(x @ W1^T), fused a_src1/a_dst1
    gemm_att_kernel<128, 128, 128, 256, 4, float>
        <<<(N + 127) / 128, 256, 0, stream>>>(x, W1, att_src1, att_dst1,
                                              h1b, a_src1, a_dst1, N);
    agg1_kernel<<<(N + 3) / 4, 256, 0, stream>>>(h1b, a_src1, a_dst1, rowptr, csr_src, b1, zb, N);

    // layer 2: h2b = bf16(zb @ W2^T), fused a_src2/a_dst2
    gemm_att_kernel<64, 48, 40, 128, 1, unsigned short>
        <<<(N + 63) / 64, 256, 0, stream>>>(zb, W2, att_src2, att_dst2,
                                            h2b, a_src2, a_dst2, N);
    agg2_kernel<<<(N + 3) / 4, 256, 0, stream>>>(h2b, a_src2, a_dst2, rowptr, csr_src, b2, out, N);
}